// Round 1
// baseline (339.126 us; speedup 1.0000x reference)
//
#include <hip/hip_runtime.h>
#include <hip/hip_bf16.h>

#define N_NODES 50000
#define N_EDGES 800000
#define IN_CH 256
#define HID 256
#define OUT_CH 128
#define N_GRAPHS 64
#define SCAN_BLOCKS 196     // ceil(50001/256)
#define M_PAD 50048         // 391 * 128
#define COUNT_BLOCKS 3125   // N_EDGES / 256
#define CVTX_BLOCKS  12512  // M_PAD*64 / 256
#define SZERO_BLOCKS 3128   // 64*50048/4 / 256  (f32x4 zeroing of S)
#define GEMM1_BLOCKS 782    // 391 * 2
#define SELF_BLOCKS  196    // self-loop S scatter, ceil(50000/256)
#define SROW 50048          // S row stride (f32)
#define T2_BLOCKS 391       // 50048 / 128
#define T2_KC 128
#define RED_BLOCKS 128      // 8192 outputs / 64

typedef __bf16 bf16x8 __attribute__((ext_vector_type(8)));
typedef float f32x4 __attribute__((ext_vector_type(4)));
typedef unsigned short u16x8 __attribute__((ext_vector_type(8)));

// bf16 <-> f32 helpers (RNE on pack)
__device__ __forceinline__ float bf2f(unsigned short u) {
    union { unsigned int i; float f; } x; x.i = ((unsigned int)u) << 16; return x.f;
}
__device__ __forceinline__ unsigned short f2bf(float f) {
    union { float f; unsigned int i; } x; x.f = f;
    unsigned int r = x.i + 0x7FFFu + ((x.i >> 16) & 1u);
    return (unsigned short)(r >> 16);
}

__device__ __forceinline__ void load16(const void* g, void* l) {
    __builtin_amdgcn_global_load_lds(
        (const __attribute__((address_space(1))) void*)g,
        (__attribute__((address_space(3))) void*)l, 16, 0, 0);
}

// final rowptr = block-local exclusive + per-256-chunk offset
__device__ __forceinline__ int rp(const int* __restrict__ rl,
                                  const int* __restrict__ boff, int i) {
    return rl[i] + boff[i >> 8];
}

// ---------------------------------------------------------------------------
// Launch A: histogram of dst (blocks 0..3124) + x f32->bf16 padded convert
// (next 12512 blocks) + S zeroing (last 3128 blocks). Independent subgraphs
// overlapped in one dispatch.
// ---------------------------------------------------------------------------
__global__ __launch_bounds__(256) void count_cvtx_kernel(const int* __restrict__ ei,
                                                         int* __restrict__ cnt,
                                                         const float* __restrict__ x,
                                                         unsigned short* __restrict__ xb,
                                                         float* __restrict__ Sp) {
    int b = blockIdx.x;
    if (b < COUNT_BLOCKS) {
        int e = b * 256 + threadIdx.x;
        atomicAdd(&cnt[ei[N_EDGES + e]], 1);
        return;
    }
    b -= COUNT_BLOCKS;
    if (b < CVTX_BLOCKS) {
        int i = b * 256 + threadIdx.x;    // float4 index
        ushort4 o;
        if (i < N_NODES * (IN_CH / 4)) {
            float4 v = ((const float4*)x)[i];
            o.x = f2bf(v.x); o.y = f2bf(v.y); o.z = f2bf(v.z); o.w = f2bf(v.w);
        } else {
            o = make_ushort4(0, 0, 0, 0);
        }
        ((ushort4*)xb)[i] = o;
        return;
    }
    // zero S: 64*50048 f32 = 800768 f32x4 stores, exactly SZERO_BLOCKS*256
    int i = (b - CVTX_BLOCKS) * 256 + threadIdx.x;
    ((f32x4*)Sp)[i] = (f32x4){0.f, 0.f, 0.f, 0.f};
}

// ---------------------------------------------------------------------------
// scan_a: block-local exclusive scan; emits dinv/invdeg; zeroes fillp;
// also per-graph node histogram (LDS bins -> global cgr).
// ---------------------------------------------------------------------------
__global__ __launch_bounds__(256) void scan_a_kernel(const int* __restrict__ cnt,
                                                     int* __restrict__ rl,
                                                     int* __restrict__ blocksum,
                                                     float* __restrict__ dinv,
                                                     float* __restrict__ invdeg,
                                                     int* __restrict__ fillp,
                                                     const int* __restrict__ batch,
                                                     int* __restrict__ cgr) {
    __shared__ int tmp[256];
    __shared__ int hist[64];
    int t = threadIdx.x;
    int i = blockIdx.x * 256 + t;
    if (t < 64) hist[t] = 0;
    int v = (i < N_NODES) ? cnt[i] : 0;
    int x = v;
    tmp[t] = x;
    __syncthreads();
    if (i < N_NODES) atomicAdd(&hist[batch[i] & 63], 1);
#pragma unroll
    for (int off = 1; off < 256; off <<= 1) {
        int y = (t >= off) ? tmp[t - off] : 0;
        __syncthreads();
        x += y;
        tmp[t] = x;
        __syncthreads();
    }
    if (i <= N_NODES) rl[i] = x - v;
    if (i < N_NODES) {
        float d = (float)v + 1.0f;         // +1 self loop
        dinv[i] = rsqrtf(d);
        invdeg[i] = 1.0f / d;
        fillp[i] = 0;
    }
    if (t == 255) blocksum[blockIdx.x] = x;
    if (t < 64 && hist[t]) atomicAdd(&cgr[t], hist[t]);
}

// ---------------------------------------------------------------------------
// blocks 0..383: W1/W2 f32 -> bf16 transposed [N][K].
// block 384: scan of block sums -> blockoff, plus invc = 1/max(cgr,1).
// ---------------------------------------------------------------------------
__global__ __launch_bounds__(256) void scanb_cvtw_kernel(
        const int* __restrict__ blocksum, int* __restrict__ blockoff,
        const float* __restrict__ W1, const float* __restrict__ W2,
        unsigned short* __restrict__ w1t, unsigned short* __restrict__ w2t,
        const int* __restrict__ cgr, float* __restrict__ invc) {
    int t = threadIdx.x;
    if (blockIdx.x < 384) {
        int i = blockIdx.x * 256 + t;                 // 0 .. 98303
        if (i < HID * IN_CH) {                        // W1t[n][k] = W1[k][n]
            int n = i >> 8, k = i & 255;
            w1t[i] = f2bf(W1[k * HID + n]);
        } else {                                      // W2t[n][k] = W2[k][n]
            int j = i - HID * IN_CH;
            int n = j >> 8, k = j & 255;
            w2t[j] = f2bf(W2[k * OUT_CH + n]);
        }
        return;
    }
    if (t < N_GRAPHS) invc[t] = 1.0f / fmaxf((float)cgr[t], 1.0f);
    __shared__ int tmp[256];
    int v = (t < SCAN_BLOCKS) ? blocksum[t] : 0;
    int x = v;
    tmp[t] = x;
    __syncthreads();
#pragma unroll
    for (int off = 1; off < 256; off <<= 1) {
        int y = (t >= off) ? tmp[t - off] : 0;
        __syncthreads();
        x += y;
        tmp[t] = x;
        __syncthreads();
    }
    if (t < SCAN_BLOCKS) blockoff[t] = x - v;
}

// ---------------------------------------------------------------------------
// GEMM tile body (128x128, 4 waves 2x2, 4x4 mfma_f32_16x16x32_bf16,
// global_load_lds width=16 staging, XOR-swizzled LDS chunks).
// TR==0: C[row][col] (row-major, stride N). TR==1: transposed packed store
// h2t[col][row] (stride M_PAD, ushort4 over 4 consecutive rows).
// ---------------------------------------------------------------------------
template <int TR>
__device__ __forceinline__ void gemm_body(const unsigned short* __restrict__ A,
                                          const unsigned short* __restrict__ Bt,
                                          unsigned short* __restrict__ C,
                                          int N, int bxx, int byy, char* As, char* Bs) {
    const int K = 256;
    int tid = threadIdx.x;
    int bm = bxx * 128;
    int bn = byy * 128;
    int lane = tid & 63, wave = tid >> 6;
    int lane15 = lane & 15, quad = lane >> 4;
    int wm0 = (wave >> 1) << 6;
    int wn0 = (wave & 1) << 6;

    int s1 = tid, s2 = tid + 256;
    int r1 = s1 >> 2, q1 = (s1 & 3) ^ ((r1 >> 1) & 3);
    int r2 = s2 >> 2, q2 = (s2 & 3) ^ ((r2 >> 1) & 3);
    const char* gA1 = (const char*)(A + (size_t)(bm + r1) * K) + (q1 << 4);
    const char* gA2 = (const char*)(A + (size_t)(bm + r2) * K) + (q2 << 4);
    const char* gB1 = (const char*)(Bt + (size_t)(bn + r1) * K) + (q1 << 4);
    const char* gB2 = (const char*)(Bt + (size_t)(bn + r2) * K) + (q2 << 4);
    char* lA1 = As + (wave << 10);
    char* lA2 = As + 4096 + (wave << 10);
    char* lB1 = Bs + (wave << 10);
    char* lB2 = Bs + 4096 + (wave << 10);

    int swm = (lane15 >> 1) & 3;
    f32x4 acc[4][4];
#pragma unroll
    for (int mt = 0; mt < 4; mt++)
#pragma unroll
        for (int nt = 0; nt < 4; nt++)
            acc[mt][nt] = (f32x4){0.f, 0.f, 0.f, 0.f};

    for (int k0 = 0; k0 < K; k0 += 32) {
        __syncthreads();
        load16(gA1 + (k0 << 1), lA1);
        load16(gA2 + (k0 << 1), lA2);
        load16(gB1 + (k0 << 1), lB1);
        load16(gB2 + (k0 << 1), lB2);
        __syncthreads();
        bf16x8 af[4], bfr[4];
#pragma unroll
        for (int t = 0; t < 4; t++) {
            int ra = wm0 + t * 16 + lane15;
            af[t] = *(const bf16x8*)(As + ra * 64 + ((quad ^ swm) << 4));
            int rb = wn0 + t * 16 + lane15;
            bfr[t] = *(const bf16x8*)(Bs + rb * 64 + ((quad ^ swm) << 4));
        }
#pragma unroll
        for (int mt = 0; mt < 4; mt++)
#pragma unroll
            for (int nt = 0; nt < 4; nt++)
                acc[mt][nt] = __builtin_amdgcn_mfma_f32_16x16x32_bf16(
                    af[mt], bfr[nt], acc[mt][nt], 0, 0, 0);
    }

#pragma unroll
    for (int mt = 0; mt < 4; mt++) {
        int rowb = bm + wm0 + mt * 16 + quad * 4;
#pragma unroll
        for (int nt = 0; nt < 4; nt++) {
            int col = bn + wn0 + nt * 16 + lane15;
            f32x4 a = acc[mt][nt];
            if (TR == 0) {
                C[(size_t)(rowb + 0) * N + col] = f2bf(a[0]);
                C[(size_t)(rowb + 1) * N + col] = f2bf(a[1]);
                C[(size_t)(rowb + 2) * N + col] = f2bf(a[2]);
                C[(size_t)(rowb + 3) * N + col] = f2bf(a[3]);
            } else {
                ushort4 o;
                o.x = f2bf(a[0]); o.y = f2bf(a[1]);
                o.z = f2bf(a[2]); o.w = f2bf(a[3]);
                *(ushort4*)(C + (size_t)col * M_PAD + rowb) = o;
            }
        }
    }
}

// Launch B: gemm1 tiles (blocks 0..781) + CSR fill + S edge scatter (next
// 3125) + S self-loop scatter (last 196); all depend only on the scans.
__global__ __launch_bounds__(256) void fill_gemm1_kernel(
        const int* __restrict__ ei,
        const int* __restrict__ rl,
        const int* __restrict__ boff,
        int* __restrict__ fillp,
        int2* __restrict__ edge2,
        const float* __restrict__ dinv,
        const float* __restrict__ invdeg,
        const int* __restrict__ batch,
        const float* __restrict__ invc,
        float* __restrict__ Sp,
        const unsigned short* __restrict__ xb,
        const unsigned short* __restrict__ w1t,
        unsigned short* __restrict__ h1b) {
    __shared__ char As[8192];
    __shared__ char Bs[8192];
    int b = blockIdx.x;
    if (b < GEMM1_BLOCKS) {
        gemm_body<0>(xb, w1t, h1b, HID, b % 391, b / 391, As, Bs);
        return;
    }
    b -= GEMM1_BLOCKS;
    if (b < COUNT_BLOCKS) {
        int e = b * 256 + threadIdx.x;
        int s = ei[e];
        int d = ei[N_EDGES + e];
        int p = rp(rl, boff, d) + atomicAdd(&fillp[d], 1);
        float w = dinv[s] * dinv[d];
        edge2[p] = make_int2(s, __float_as_int(w));
        int gd = batch[d];
        atomicAdd(&Sp[(size_t)gd * SROW + s], w * invc[gd]);
        return;
    }
    // self-loop contribution into S
    int i = (b - COUNT_BLOCKS) * 256 + threadIdx.x;
    if (i < N_NODES) {
        int g = batch[i];
        atomicAdd(&Sp[(size_t)g * SROW + i], invdeg[i] * invc[g]);
    }
}

// standalone gemm for conv2: writes h2 TRANSPOSED (h2t[c][node])
__global__ __launch_bounds__(256) void gemm_mfma_kernel(
        const unsigned short* __restrict__ A,
        const unsigned short* __restrict__ Bt,
        unsigned short* __restrict__ C,
        int N) {
    __shared__ char As[8192];
    __shared__ char Bs[8192];
    gemm_body<1>(A, Bt, C, N, blockIdx.x, blockIdx.y, As, Bs);
}

// ---------------------------------------------------------------------------
// GCN aggregation, 256ch (conv1): wave/node, lane = 4ch, bf16 ushort4
// gathers (512B/wave), 8-edge unroll, f32 accumulate, ELU, bf16 output.
// Grid extended to M_PAD: pad rows get zeroed (so gemm2 -> h2t pads = 0,
// making the S-zero-pad x h2t-pad MFMA products exactly 0, never NaN).
// ---------------------------------------------------------------------------
#define ACC4(V, W) \
    acc.x += bf2f(V.x) * W; acc.y += bf2f(V.y) * W; \
    acc.z += bf2f(V.z) * W; acc.w += bf2f(V.w) * W;

__global__ __launch_bounds__(256) void agg1_kernel(const unsigned short* __restrict__ h,
                                                   const float* __restrict__ bias,
                                                   const int* __restrict__ rl,
                                                   const int* __restrict__ boff,
                                                   const int2* __restrict__ edge2,
                                                   const float* __restrict__ invdeg,
                                                   unsigned short* __restrict__ out) {
    int node = blockIdx.x * 4 + (threadIdx.x >> 6);
    int lane = threadIdx.x & 63;
    if (node >= N_NODES) {
        if (node < M_PAD)
            ((ushort4*)out)[(size_t)node * 64 + lane] = make_ushort4(0, 0, 0, 0);
        return;
    }
    const ushort4* h4 = (const ushort4*)h;
    float id = invdeg[node];
    ushort4 sv = h4[(size_t)node * 64 + lane];
    float4 acc = make_float4(bf2f(sv.x) * id, bf2f(sv.y) * id,
                             bf2f(sv.z) * id, bf2f(sv.w) * id);
    int e0 = rp(rl, boff, node);
    int e1 = rp(rl, boff, node + 1);
    int e = e0;
    for (; e + 7 < e1; e += 8) {
        int2 ed[8];
        ushort4 v[8];
#pragma unroll
        for (int j = 0; j < 8; j++) ed[j] = edge2[e + j];
#pragma unroll
        for (int j = 0; j < 8; j++) v[j] = h4[(size_t)ed[j].x * 64 + lane];
#pragma unroll
        for (int j = 0; j < 8; j++) {
            float w = __int_as_float(ed[j].y);
            ACC4(v[j], w);
        }
    }
    for (; e + 3 < e1; e += 4) {
        int2 ed[4];
        ushort4 v[4];
#pragma unroll
        for (int j = 0; j < 4; j++) ed[j] = edge2[e + j];
#pragma unroll
        for (int j = 0; j < 4; j++) v[j] = h4[(size_t)ed[j].x * 64 + lane];
#pragma unroll
        for (int j = 0; j < 4; j++) {
            float w = __int_as_float(ed[j].y);
            ACC4(v[j], w);
        }
    }
    for (; e < e1; e++) {
        int2 ed0 = edge2[e];
        float w0 = __int_as_float(ed0.y);
        ushort4 v0 = h4[(size_t)ed0.x * 64 + lane];
        ACC4(v0, w0);
    }
    float4 bb = ((const float4*)bias)[lane];
    acc.x += bb.x; acc.y += bb.y; acc.z += bb.z; acc.w += bb.w;
    acc.x = acc.x > 0.f ? acc.x : expm1f(acc.x);
    acc.y = acc.y > 0.f ? acc.y : expm1f(acc.y);
    acc.z = acc.z > 0.f ? acc.z : expm1f(acc.z);
    acc.w = acc.w > 0.f ? acc.w : expm1f(acc.w);
    ushort4 o;
    o.x = f2bf(acc.x); o.y = f2bf(acc.y); o.z = f2bf(acc.z); o.w = f2bf(acc.w);
    ((ushort4*)out)[(size_t)node * 64 + lane] = o;
}

// ---------------------------------------------------------------------------
// t2 = S @ h2 : [64 x 50048] x [50048 x 128] MFMA GEMM, K-split over 391
// blocks (Kc=128). A = S (f32, split in-kernel into bf16 hi+lo limbs, two
// MFMAs sharing the B fragment -> ~2^-17 weight error, f32 accumulate).
// B = h2t (k-contiguous rows). Pure streaming: no gathers, no LDS.
// Partials to part[b][64][128].
// ---------------------------------------------------------------------------
__global__ __launch_bounds__(256) void t2_kernel(const float* __restrict__ Sp,
                                                 const unsigned short* __restrict__ h2t,
                                                 float* __restrict__ part) {
    int b = blockIdx.x;
    int k0 = b * T2_KC;
    int tid = threadIdx.x;
    int lane = tid & 63, wave = tid >> 6;
    int lane15 = lane & 15, quad = lane >> 4;
    int cb = wave << 5;                    // 32 channels per wave
    f32x4 acc[4][2];
#pragma unroll
    for (int m = 0; m < 4; m++) {
        acc[m][0] = (f32x4){0.f, 0.f, 0.f, 0.f};
        acc[m][1] = (f32x4){0.f, 0.f, 0.f, 0.f};
    }
    const unsigned short* hr0 = h2t + (size_t)(cb + lane15) * M_PAD;
    const unsigned short* hr1 = h2t + (size_t)(cb + 16 + lane15) * M_PAD;
#pragma unroll
    for (int ks = 0; ks < T2_KC / 32; ks++) {
        int k = k0 + ks * 32 + quad * 8;
        bf16x8 b0 = *(const bf16x8*)(hr0 + k);
        bf16x8 b1 = *(const bf16x8*)(hr1 + k);
#pragma unroll
        for (int m = 0; m < 4; m++) {
            const float* ap = Sp + (size_t)(m * 16 + lane15) * SROW + k;
            f32x4 v0 = *(const f32x4*)ap;
            f32x4 v1 = *(const f32x4*)(ap + 4);
            u16x8 hu, lu;
#pragma unroll
            for (int j = 0; j < 4; j++) {
                unsigned int e0 = __float_as_uint(v0[j]);
                hu[j] = (unsigned short)(e0 >> 16);                       // trunc hi
                lu[j] = f2bf(v0[j] - __uint_as_float(e0 & 0xFFFF0000u));  // residual
                unsigned int e1 = __float_as_uint(v1[j]);
                hu[j + 4] = (unsigned short)(e1 >> 16);
                lu[j + 4] = f2bf(v1[j] - __uint_as_float(e1 & 0xFFFF0000u));
            }
            bf16x8 ah = __builtin_bit_cast(bf16x8, hu);
            bf16x8 al = __builtin_bit_cast(bf16x8, lu);
            acc[m][0] = __builtin_amdgcn_mfma_f32_16x16x32_bf16(ah, b0, acc[m][0], 0, 0, 0);
            acc[m][0] = __builtin_amdgcn_mfma_f32_16x16x32_bf16(al, b0, acc[m][0], 0, 0, 0);
            acc[m][1] = __builtin_amdgcn_mfma_f32_16x16x32_bf16(ah, b1, acc[m][1], 0, 0, 0);
            acc[m][1] = __builtin_amdgcn_mfma_f32_16x16x32_bf16(al, b1, acc[m][1], 0, 0, 0);
        }
    }
    float* pb = part + (size_t)b * (N_GRAPHS * OUT_CH);
#pragma unroll
    for (int m = 0; m < 4; m++) {
        int g0 = m * 16 + quad * 4;
#pragma unroll
        for (int nt = 0; nt < 2; nt++) {
            int c = cb + nt * 16 + lane15;
            f32x4 a = acc[m][nt];
#pragma unroll
            for (int j = 0; j < 4; j++)
                pb[(g0 + j) * OUT_CH + c] = a[j];
        }
    }
}

// reduce partials over 391 blocks, add bias, empty-graph guard, write out.
__global__ __launch_bounds__(256) void t2red_kernel(const float* __restrict__ part,
                                                    const float* __restrict__ b2,
                                                    const int* __restrict__ cgr,
                                                    float* __restrict__ out) {
    __shared__ float red[4][64];
    int tid = threadIdx.x;
    int q = tid >> 6, l = tid & 63;
    int o = blockIdx.x * 64 + l;
    float s = 0.f;
    for (int i = q; i < T2_BLOCKS; i += 4)
        s += part[(size_t)i * (N_GRAPHS * OUT_CH) + o];
    red[q][l] = s;
    __syncthreads();
    if (tid < 64) {
        float tot = red[0][l] + red[1][l] + red[2][l] + red[3][l];
        int g = o >> 7, c = o & 127;
        out[o] = (cgr[g] > 0) ? tot + b2[c] : 0.f;
    }
}

// ---------------------------------------------------------------------------
extern "C" void kernel_launch(void* const* d_in, const int* in_sizes, int n_in,
                              void* d_out, int out_size, void* d_ws, size_t ws_size,
                              hipStream_t stream) {
    const float* x  = (const float*)d_in[0];
    const float* W1 = (const float*)d_in[1];
    const float* b1 = (const float*)d_in[2];
    const float* W2 = (const float*)d_in[3];
    const float* b2 = (const float*)d_in[4];
    const int*   ei = (const int*)d_in[5];
    const int*   batch = (const int*)d_in[6];
    float* out = (float*)d_out;

    // workspace layout (16B-aligned by construction)
    unsigned short* xb  = (unsigned short*)d_ws;                 // M_PAD*256 bf16
    unsigned short* h1b = xb  + (size_t)M_PAD * IN_CH;           // M_PAD*256 bf16
    unsigned short* hBb = h1b + (size_t)M_PAD * HID;             // M_PAD*256 bf16
    unsigned short* h2t = hBb + (size_t)M_PAD * HID;             // 128*M_PAD bf16 (transposed)
    unsigned short* w1t = h2t + (size_t)OUT_CH * M_PAD;          // 256*256
    unsigned short* w2t = w1t + HID * IN_CH;                     // 128*256
    float* dinv   = (float*)(w2t + OUT_CH * HID);                // 50000
    float* invdeg = dinv + N_NODES;                              // 50000
    int*   rl     = (int*)(invdeg + N_NODES);                    // 50001 (pad 50016)
    int2*  edge2  = (int2*)(rl + 50016);                         // 800000 int2
    int*   cnt    = (int*)(edge2 + N_EDGES);                     // 50000 } memset
    int*   cgr    = cnt + N_NODES;                               // 64    } together
    int*   fillp  = cgr + N_GRAPHS;                              // 50000 (zeroed in scan_a)
    float* Sp     = (float*)(fillp + N_NODES);                   // 64*50048 f32 (zeroed in launch A)
    int*   blocksum = (int*)(Sp + (size_t)N_GRAPHS * SROW);      // 256
    int*   blockoff = blocksum + 256;                            // 256
    float* invc   = (float*)(blockoff + 256);                    // 64
    float* part   = (float*)h1b;   // t2 partials alias h1b (dead after agg1)

    hipMemsetAsync(cnt, 0, (size_t)(N_NODES + N_GRAPHS) * 4, stream);

    // A: histogram + x convert + S zero (independent, one launch)
    count_cvtx_kernel<<<COUNT_BLOCKS + CVTX_BLOCKS + SZERO_BLOCKS, 256, 0, stream>>>(
        ei, cnt, x, xb, Sp);
    // scan phase (also zeroes fillp, builds per-graph histogram)
    scan_a_kernel<<<SCAN_BLOCKS, 256, 0, stream>>>(cnt, rl, blocksum, dinv, invdeg,
                                                   fillp, batch, cgr);
    // weight convert + blocksum scan + invc
    scanb_cvtw_kernel<<<385, 256, 0, stream>>>(blocksum, blockoff, W1, W2, w1t, w2t,
                                               cgr, invc);
    // B: gemm1 tiles + CSR fill + S scatter (one launch)
    fill_gemm1_kernel<<<GEMM1_BLOCKS + COUNT_BLOCKS + SELF_BLOCKS, 256, 0, stream>>>(
        ei, rl, blockoff, fillp, edge2, dinv, invdeg, batch, invc, Sp, xb, w1t, h1b);
    // conv1 aggregate (+ELU); pads zeroed
    agg1_kernel<<<M_PAD / 4, 256, 0, stream>>>(h1b, b1, rl, blockoff,
                                               edge2, invdeg, hBb);
    // conv2 GEMM (transposed output h2t)
    dim3 g2(M_PAD / 128, OUT_CH / 128);
    gemm_mfma_kernel<<<g2, 256, 0, stream>>>(hBb, w2t, h2t, OUT_CH);
    // fused agg2+pool+mean as dense streaming GEMM out = S @ h2 + b2
    t2_kernel<<<T2_BLOCKS, 256, 0, stream>>>(Sp, h2t, part);
    t2red_kernel<<<RED_BLOCKS, 256, 0, stream>>>(part, b2, cgr, out);
}

// Round 2
// 321.801 us; speedup vs baseline: 1.0538x; 1.0538x over previous
//
#include <hip/hip_runtime.h>
#include <hip/hip_bf16.h>

#define N_NODES 50000
#define N_EDGES 800000
#define IN_CH 256
#define HID 256
#define OUT_CH 128
#define N_GRAPHS 64
#define SCAN_BLOCKS 196     // ceil(50001/256)
#define M_PAD 50048         // 391 * 128
#define COUNT_BLOCKS 3125   // N_EDGES / 256
#define CVTX_BLOCKS  12512  // M_PAD*64 / 256
#define GEMM1_BLOCKS 782    // 391 * 2

typedef __bf16 bf16x8 __attribute__((ext_vector_type(8)));
typedef float f32x4 __attribute__((ext_vector_type(4)));
typedef float f32x2 __attribute__((ext_vector_type(2)));

// bf16 <-> f32 helpers (RNE on pack)
__device__ __forceinline__ float bf2f(unsigned short u) {
    union { unsigned int i; float f; } x; x.i = ((unsigned int)u) << 16; return x.f;
}
__device__ __forceinline__ unsigned short f2bf(float f) {
    union { float f; unsigned int i; } x; x.f = f;
    unsigned int r = x.i + 0x7FFFu + ((x.i >> 16) & 1u);
    return (unsigned short)(r >> 16);
}

// packed bf16x2 (as uint) -> 2 floats: 1 shift + 1 and
__device__ __forceinline__ float lo_f(unsigned int u) {
    return __uint_as_float(u << 16);
}
__device__ __forceinline__ float hi_f(unsigned int u) {
    return __uint_as_float(u & 0xFFFF0000u);
}

__device__ __forceinline__ void load16(const void* g, void* l) {
    __builtin_amdgcn_global_load_lds(
        (const __attribute__((address_space(1))) void*)g,
        (__attribute__((address_space(3))) void*)l, 16, 0, 0);
}

// final rowptr = block-local exclusive + per-256-chunk offset
__device__ __forceinline__ int rp(const int* __restrict__ rl,
                                  const int* __restrict__ boff, int i) {
    return rl[i] + boff[i >> 8];
}

// ---------------------------------------------------------------------------
// Launch A: histogram of dst (blocks 0..3124) + x f32->bf16 padded convert
// (blocks 3125..15636). Independent subgraphs overlapped in one dispatch.
// ---------------------------------------------------------------------------
__global__ __launch_bounds__(256) void count_cvtx_kernel(const int* __restrict__ ei,
                                                         int* __restrict__ cnt,
                                                         const float* __restrict__ x,
                                                         unsigned short* __restrict__ xb) {
    int b = blockIdx.x;
    if (b < COUNT_BLOCKS) {
        int e = b * 256 + threadIdx.x;
        atomicAdd(&cnt[ei[N_EDGES + e]], 1);
        return;
    }
    int i = (b - COUNT_BLOCKS) * 256 + threadIdx.x;    // float4 index
    ushort4 o;
    if (i < N_NODES * (IN_CH / 4)) {
        float4 v = ((const float4*)x)[i];
        o.x = f2bf(v.x); o.y = f2bf(v.y); o.z = f2bf(v.z); o.w = f2bf(v.w);
    } else {
        o = make_ushort4(0, 0, 0, 0);
    }
    ((ushort4*)xb)[i] = o;
}

// ---------------------------------------------------------------------------
// scan_a: block-local exclusive scan; emits dinv/invdeg; zeroes fillp;
// also graph boundary detection (batch sorted) -> rstart[0..64].
// ---------------------------------------------------------------------------
__global__ __launch_bounds__(256) void scan_a_kernel(const int* __restrict__ cnt,
                                                     int* __restrict__ rl,
                                                     int* __restrict__ blocksum,
                                                     float* __restrict__ dinv,
                                                     float* __restrict__ invdeg,
                                                     int* __restrict__ fillp,
                                                     const int* __restrict__ batch,
                                                     int* __restrict__ rstart) {
    __shared__ int tmp[256];
    int t = threadIdx.x;
    int i = blockIdx.x * 256 + t;
    int v = (i < N_NODES) ? cnt[i] : 0;
    int x = v;
    tmp[t] = x;
    __syncthreads();
    if (i < N_NODES) {
        int bg = batch[i];
        int bp = (i > 0) ? batch[i - 1] : -1;
        for (int g = bp + 1; g <= bg; g++) rstart[g] = i;   // boundary (rare)
        if (i == N_NODES - 1)
            for (int g = bg + 1; g <= N_GRAPHS; g++) rstart[g] = N_NODES;
    }
#pragma unroll
    for (int off = 1; off < 256; off <<= 1) {
        int y = (t >= off) ? tmp[t - off] : 0;
        __syncthreads();
        x += y;
        tmp[t] = x;
        __syncthreads();
    }
    if (i <= N_NODES) rl[i] = x - v;
    if (i < N_NODES) {
        float d = (float)v + 1.0f;         // +1 self loop
        dinv[i] = rsqrtf(d);
        invdeg[i] = 1.0f / d;
        fillp[i] = 0;
    }
    if (t == 255) blocksum[blockIdx.x] = x;
}

// ---------------------------------------------------------------------------
// blocks 0..383: W1/W2 f32 -> bf16 transposed [N][K].
// block 384: scan of block sums -> blockoff.
// ---------------------------------------------------------------------------
__global__ __launch_bounds__(256) void scanb_cvtw_kernel(
        const int* __restrict__ blocksum, int* __restrict__ blockoff,
        const float* __restrict__ W1, const float* __restrict__ W2,
        unsigned short* __restrict__ w1t, unsigned short* __restrict__ w2t) {
    int t = threadIdx.x;
    if (blockIdx.x < 384) {
        int i = blockIdx.x * 256 + t;                 // 0 .. 98303
        if (i < HID * IN_CH) {                        // W1t[n][k] = W1[k][n]
            int n = i >> 8, k = i & 255;
            w1t[i] = f2bf(W1[k * HID + n]);
        } else {                                      // W2t[n][k] = W2[k][n]
            int j = i - HID * IN_CH;
            int n = j >> 8, k = j & 255;
            w2t[j] = f2bf(W2[k * OUT_CH + n]);
        }
        return;
    }
    __shared__ int tmp[256];
    int v = (t < SCAN_BLOCKS) ? blocksum[t] : 0;
    int x = v;
    tmp[t] = x;
    __syncthreads();
#pragma unroll
    for (int off = 1; off < 256; off <<= 1) {
        int y = (t >= off) ? tmp[t - off] : 0;
        __syncthreads();
        x += y;
        tmp[t] = x;
        __syncthreads();
    }
    if (t < SCAN_BLOCKS) blockoff[t] = x - v;
}

// ---------------------------------------------------------------------------
// GEMM tile body (128x128, 4 waves 2x2, 4x4 mfma_f32_16x16x32_bf16,
// global_load_lds width=16 staging, XOR-swizzled LDS chunks).
// ---------------------------------------------------------------------------
__device__ __forceinline__ void gemm_body(const unsigned short* __restrict__ A,
                                          const unsigned short* __restrict__ Bt,
                                          unsigned short* __restrict__ C,
                                          int N, int bxx, int byy, char* As, char* Bs) {
    const int K = 256;
    int tid = threadIdx.x;
    int bm = bxx * 128;
    int bn = byy * 128;
    int lane = tid & 63, wave = tid >> 6;
    int lane15 = lane & 15, quad = lane >> 4;
    int wm0 = (wave >> 1) << 6;
    int wn0 = (wave & 1) << 6;

    int s1 = tid, s2 = tid + 256;
    int r1 = s1 >> 2, q1 = (s1 & 3) ^ ((r1 >> 1) & 3);
    int r2 = s2 >> 2, q2 = (s2 & 3) ^ ((r2 >> 1) & 3);
    const char* gA1 = (const char*)(A + (size_t)(bm + r1) * K) + (q1 << 4);
    const char* gA2 = (const char*)(A + (size_t)(bm + r2) * K) + (q2 << 4);
    const char* gB1 = (const char*)(Bt + (size_t)(bn + r1) * K) + (q1 << 4);
    const char* gB2 = (const char*)(Bt + (size_t)(bn + r2) * K) + (q2 << 4);
    char* lA1 = As + (wave << 10);
    char* lA2 = As + 4096 + (wave << 10);
    char* lB1 = Bs + (wave << 10);
    char* lB2 = Bs + 4096 + (wave << 10);

    int swm = (lane15 >> 1) & 3;
    f32x4 acc[4][4];
#pragma unroll
    for (int mt = 0; mt < 4; mt++)
#pragma unroll
        for (int nt = 0; nt < 4; nt++)
            acc[mt][nt] = (f32x4){0.f, 0.f, 0.f, 0.f};

    for (int k0 = 0; k0 < K; k0 += 32) {
        __syncthreads();
        load16(gA1 + (k0 << 1), lA1);
        load16(gA2 + (k0 << 1), lA2);
        load16(gB1 + (k0 << 1), lB1);
        load16(gB2 + (k0 << 1), lB2);
        __syncthreads();
        bf16x8 af[4], bfr[4];
#pragma unroll
        for (int t = 0; t < 4; t++) {
            int ra = wm0 + t * 16 + lane15;
            af[t] = *(const bf16x8*)(As + ra * 64 + ((quad ^ swm) << 4));
            int rb = wn0 + t * 16 + lane15;
            bfr[t] = *(const bf16x8*)(Bs + rb * 64 + ((quad ^ swm) << 4));
        }
#pragma unroll
        for (int mt = 0; mt < 4; mt++)
#pragma unroll
            for (int nt = 0; nt < 4; nt++)
                acc[mt][nt] = __builtin_amdgcn_mfma_f32_16x16x32_bf16(
                    af[mt], bfr[nt], acc[mt][nt], 0, 0, 0);
    }

#pragma unroll
    for (int mt = 0; mt < 4; mt++) {
        int rowb = bm + wm0 + mt * 16 + quad * 4;
#pragma unroll
        for (int nt = 0; nt < 4; nt++) {
            int col = bn + wn0 + nt * 16 + lane15;
            f32x4 a = acc[mt][nt];
            C[(size_t)(rowb + 0) * N + col] = f2bf(a[0]);
            C[(size_t)(rowb + 1) * N + col] = f2bf(a[1]);
            C[(size_t)(rowb + 2) * N + col] = f2bf(a[2]);
            C[(size_t)(rowb + 3) * N + col] = f2bf(a[3]);
        }
    }
}

// Launch B: gemm1 tiles (blocks 0..781) + CSR fill (rest); both depend only
// on the scans. gemm blocks first so MFMA work starts immediately.
__global__ __launch_bounds__(256) void fill_gemm1_kernel(
        const int* __restrict__ ei,
        const int* __restrict__ rl,
        const int* __restrict__ boff,
        int* __restrict__ fillp,
        int2* __restrict__ edge2,
        const float* __restrict__ dinv,
        const unsigned short* __restrict__ xb,
        const unsigned short* __restrict__ w1t,
        unsigned short* __restrict__ h1b) {
    __shared__ char As[8192];
    __shared__ char Bs[8192];
    int b = blockIdx.x;
    if (b < GEMM1_BLOCKS) {
        gemm_body(xb, w1t, h1b, HID, b % 391, b / 391, As, Bs);
        return;
    }
    int e = (b - GEMM1_BLOCKS) * 256 + threadIdx.x;
    if (e >= N_EDGES) return;
    int s = ei[e];
    int d = ei[N_EDGES + e];
    int p = rp(rl, boff, d) + atomicAdd(&fillp[d], 1);
    float w = dinv[s] * dinv[d];
    edge2[p] = make_int2(s, __float_as_int(w));
}

// standalone gemm for conv2
__global__ __launch_bounds__(256) void gemm_mfma_kernel(
        const unsigned short* __restrict__ A,
        const unsigned short* __restrict__ Bt,
        unsigned short* __restrict__ C,
        int N) {
    __shared__ char As[8192];
    __shared__ char Bs[8192];
    gemm_body(A, Bt, C, N, blockIdx.x, blockIdx.y, As, Bs);
}

// ---------------------------------------------------------------------------
// GCN aggregation, 256ch (conv1): wave/node, lane = 4ch. Gathers loaded as
// packed uint2 (512B/wave), expanded with shift/mask into f32x4 vector FMA
// (v_pk_fma_f32), 16-edge unroll for deep MLP, f32 accumulate, ELU, bf16 out.
// ---------------------------------------------------------------------------
__global__ __launch_bounds__(256) void agg1_kernel(const unsigned short* __restrict__ h,
                                                   const float* __restrict__ bias,
                                                   const int* __restrict__ rl,
                                                   const int* __restrict__ boff,
                                                   const int2* __restrict__ edge2,
                                                   const float* __restrict__ invdeg,
                                                   unsigned short* __restrict__ out) {
    int node = blockIdx.x * 4 + (threadIdx.x >> 6);
    if (node >= N_NODES) return;
    int lane = threadIdx.x & 63;
    const uint2* h4 = (const uint2*)h;
    float id = invdeg[node];
    uint2 sv = h4[(size_t)node * 64 + lane];
    f32x4 acc = (f32x4){lo_f(sv.x) * id, hi_f(sv.x) * id,
                        lo_f(sv.y) * id, hi_f(sv.y) * id};
    int e0 = rp(rl, boff, node);
    int e1 = rp(rl, boff, node + 1);
    int e = e0;
    for (; e + 15 < e1; e += 16) {
        int2 ed[16];
        uint2 v[16];
#pragma unroll
        for (int j = 0; j < 16; j++) ed[j] = edge2[e + j];
#pragma unroll
        for (int j = 0; j < 16; j++) v[j] = h4[(size_t)ed[j].x * 64 + lane];
#pragma unroll
        for (int j = 0; j < 16; j++) {
            float w = __int_as_float(ed[j].y);
            f32x4 vf = (f32x4){lo_f(v[j].x), hi_f(v[j].x),
                               lo_f(v[j].y), hi_f(v[j].y)};
            acc += vf * w;
        }
    }
    for (; e + 7 < e1; e += 8) {
        int2 ed[8];
        uint2 v[8];
#pragma unroll
        for (int j = 0; j < 8; j++) ed[j] = edge2[e + j];
#pragma unroll
        for (int j = 0; j < 8; j++) v[j] = h4[(size_t)ed[j].x * 64 + lane];
#pragma unroll
        for (int j = 0; j < 8; j++) {
            float w = __int_as_float(ed[j].y);
            f32x4 vf = (f32x4){lo_f(v[j].x), hi_f(v[j].x),
                               lo_f(v[j].y), hi_f(v[j].y)};
            acc += vf * w;
        }
    }
    for (; e + 3 < e1; e += 4) {
        int2 ed[4];
        uint2 v[4];
#pragma unroll
        for (int j = 0; j < 4; j++) ed[j] = edge2[e + j];
#pragma unroll
        for (int j = 0; j < 4; j++) v[j] = h4[(size_t)ed[j].x * 64 + lane];
#pragma unroll
        for (int j = 0; j < 4; j++) {
            float w = __int_as_float(ed[j].y);
            f32x4 vf = (f32x4){lo_f(v[j].x), hi_f(v[j].x),
                               lo_f(v[j].y), hi_f(v[j].y)};
            acc += vf * w;
        }
    }
    for (; e < e1; e++) {
        int2 ed0 = edge2[e];
        float w0 = __int_as_float(ed0.y);
        uint2 v0 = h4[(size_t)ed0.x * 64 + lane];
        f32x4 vf = (f32x4){lo_f(v0.x), hi_f(v0.x), lo_f(v0.y), hi_f(v0.y)};
        acc += vf * w0;
    }
    float4 bb = ((const float4*)bias)[lane];
    acc[0] += bb.x; acc[1] += bb.y; acc[2] += bb.z; acc[3] += bb.w;
    acc[0] = acc[0] > 0.f ? acc[0] : expm1f(acc[0]);
    acc[1] = acc[1] > 0.f ? acc[1] : expm1f(acc[1]);
    acc[2] = acc[2] > 0.f ? acc[2] : expm1f(acc[2]);
    acc[3] = acc[3] > 0.f ? acc[3] : expm1f(acc[3]);
    ushort4 o;
    o.x = f2bf(acc[0]); o.y = f2bf(acc[1]); o.z = f2bf(acc[2]); o.w = f2bf(acc[3]);
    ((ushort4*)out)[(size_t)node * 64 + lane] = o;
}

// 128ch (conv2): wave/node, lane = 2ch (one packed uint), 16-edge unroll.
__global__ __launch_bounds__(256) void agg2_kernel(const unsigned short* __restrict__ h,
                                                   const float* __restrict__ bias,
                                                   const int* __restrict__ rl,
                                                   const int* __restrict__ boff,
                                                   const int2* __restrict__ edge2,
                                                   const float* __restrict__ invdeg,
                                                   unsigned short* __restrict__ out) {
    int node = blockIdx.x * 4 + (threadIdx.x >> 6);
    if (node >= N_NODES) return;
    int lane = threadIdx.x & 63;
    const unsigned int* h2 = (const unsigned int*)h;
    float id = invdeg[node];
    unsigned int sv = h2[(size_t)node * 64 + lane];
    f32x2 acc = (f32x2){lo_f(sv) * id, hi_f(sv) * id};
    int e0 = rp(rl, boff, node);
    int e1 = rp(rl, boff, node + 1);
    int e = e0;
    for (; e + 15 < e1; e += 16) {
        int2 ed[16];
        unsigned int v[16];
#pragma unroll
        for (int j = 0; j < 16; j++) ed[j] = edge2[e + j];
#pragma unroll
        for (int j = 0; j < 16; j++) v[j] = h2[(size_t)ed[j].x * 64 + lane];
#pragma unroll
        for (int j = 0; j < 16; j++) {
            float w = __int_as_float(ed[j].y);
            acc += (f32x2){lo_f(v[j]), hi_f(v[j])} * w;
        }
    }
    for (; e + 7 < e1; e += 8) {
        int2 ed[8];
        unsigned int v[8];
#pragma unroll
        for (int j = 0; j < 8; j++) ed[j] = edge2[e + j];
#pragma unroll
        for (int j = 0; j < 8; j++) v[j] = h2[(size_t)ed[j].x * 64 + lane];
#pragma unroll
        for (int j = 0; j < 8; j++) {
            float w = __int_as_float(ed[j].y);
            acc += (f32x2){lo_f(v[j]), hi_f(v[j])} * w;
        }
    }
    for (; e + 3 < e1; e += 4) {
        int2 ed[4];
        unsigned int v[4];
#pragma unroll
        for (int j = 0; j < 4; j++) ed[j] = edge2[e + j];
#pragma unroll
        for (int j = 0; j < 4; j++) v[j] = h2[(size_t)ed[j].x * 64 + lane];
#pragma unroll
        for (int j = 0; j < 4; j++) {
            float w = __int_as_float(ed[j].y);
            acc += (f32x2){lo_f(v[j]), hi_f(v[j])} * w;
        }
    }
    for (; e < e1; e++) {
        int2 ed0 = edge2[e];
        float w0 = __int_as_float(ed0.y);
        unsigned int v0 = h2[(size_t)ed0.x * 64 + lane];
        acc += (f32x2){lo_f(v0), hi_f(v0)} * w0;
    }
    float2 bb = ((const float2*)bias)[lane];
    acc[0] += bb.x; acc[1] += bb.y;
    ushort2 o;
    o.x = f2bf(acc[0]); o.y = f2bf(acc[1]);
    ((ushort2*)out)[(size_t)node * 64 + lane] = o;
}

// ---------------------------------------------------------------------------
// Global mean pool: batch is sorted, so graph g owns node range
// [rstart[g], rstart[g+1]). One 512-thread block per graph: contiguous
// streaming reads, zero atomics, divide + write out directly (no final
// kernel, no gcnt).
// ---------------------------------------------------------------------------
__global__ __launch_bounds__(512) void pool_kernel(const unsigned short* __restrict__ h,
                                                   const int* __restrict__ rstart,
                                                   float* __restrict__ out) {
    int g = blockIdx.x;
    int n0 = rstart[g], n1 = rstart[g + 1];
    int c2 = threadIdx.x & 63;         // packed channel pair 0..63
    int row = threadIdx.x >> 6;        // 0..7
    const unsigned int* h2 = (const unsigned int*)h;
    float ax = 0.f, ay = 0.f;
    for (int n = n0 + row; n < n1; n += 8) {
        unsigned int u = h2[(size_t)n * 64 + c2];
        ax += lo_f(u);
        ay += hi_f(u);
    }
    __shared__ float red[8][128];
    red[row][c2 * 2] = ax;
    red[row][c2 * 2 + 1] = ay;
    __syncthreads();
    if (threadIdx.x < 128) {
        int c = threadIdx.x;
        float s = 0.f;
#pragma unroll
        for (int r = 0; r < 8; r++) s += red[r][c];
        int cn = n1 - n0;
        out[g * OUT_CH + c] = (cn > 0) ? s / (float)cn : 0.f;
    }
}

// ---------------------------------------------------------------------------
extern "C" void kernel_launch(void* const* d_in, const int* in_sizes, int n_in,
                              void* d_out, int out_size, void* d_ws, size_t ws_size,
                              hipStream_t stream) {
    const float* x  = (const float*)d_in[0];
    const float* W1 = (const float*)d_in[1];
    const float* b1 = (const float*)d_in[2];
    const float* W2 = (const float*)d_in[3];
    const float* b2 = (const float*)d_in[4];
    const int*   ei = (const int*)d_in[5];
    const int*   batch = (const int*)d_in[6];
    float* out = (float*)d_out;

    // workspace layout (16B-aligned by construction)
    unsigned short* xb  = (unsigned short*)d_ws;                 // M_PAD*256 bf16
    unsigned short* h1b = xb  + (size_t)M_PAD * IN_CH;           // M_PAD*256 bf16
    unsigned short* hBb = h1b + (size_t)M_PAD * HID;             // M_PAD*256 bf16
    unsigned short* h2b = hBb + (size_t)M_PAD * HID;             // M_PAD*128 bf16
    unsigned short* w1t = h2b + (size_t)M_PAD * OUT_CH;          // 256*256
    unsigned short* w2t = w1t + HID * IN_CH;                     // 128*256
    unsigned short* hcb = xb;   // agg2 bf16 out aliases xb (dead after gemm1)
    float* dinv   = (float*)(w2t + OUT_CH * HID);                // 50000
    float* invdeg = dinv + N_NODES;                              // 50000
    int*   rl     = (int*)(invdeg + N_NODES);                    // 50001 (pad 50016)
    int2*  edge2  = (int2*)(rl + 50016);                         // 800000 int2
    int*   cnt    = (int*)(edge2 + N_EDGES);                     // 50000 (memset)
    int*   fillp  = cnt + N_NODES;                               // 50000 (zeroed in scan_a)
    int*   blocksum = fillp + N_NODES;                           // 256
    int*   blockoff = blocksum + 256;                            // 256
    int*   rstart   = blockoff + 256;                            // 65 (pad 80)

    hipMemsetAsync(cnt, 0, (size_t)N_NODES * 4, stream);

    // A: histogram + x convert (independent, one launch)
    count_cvtx_kernel<<<COUNT_BLOCKS + CVTX_BLOCKS, 256, 0, stream>>>(ei, cnt, x, xb);
    // scan phase (also zeroes fillp, detects graph boundaries)
    scan_a_kernel<<<SCAN_BLOCKS, 256, 0, stream>>>(cnt, rl, blocksum, dinv, invdeg,
                                                   fillp, batch, rstart);
    // weight convert + blocksum scan
    scanb_cvtw_kernel<<<385, 256, 0, stream>>>(blocksum, blockoff, W1, W2, w1t, w2t);
    // B: gemm1 tiles + CSR fill (one launch)
    fill_gemm1_kernel<<<GEMM1_BLOCKS + COUNT_BLOCKS, 256, 0, stream>>>(
        ei, rl, blockoff, fillp, edge2, dinv, xb, w1t, h1b);
    // conv1 aggregate (+ELU)
    agg1_kernel<<<(N_NODES + 3) / 4, 256, 0, stream>>>(h1b, b1, rl, blockoff,
                                                       edge2, invdeg, hBb);
    // conv2
    dim3 g2(M_PAD / 128, OUT_CH / 128);
    gemm_mfma_kernel<<<g2, 256, 0, stream>>>(hBb, w2t, h2b, OUT_CH);
    agg2_kernel<<<(N_NODES + 3) / 4, 256, 0, stream>>>(h2b, b2, rl, blockoff,
                                                       edge2, invdeg, hcb);
    // mean pool: block-per-graph, no atomics, writes out directly
    pool_kernel<<<N_GRAPHS, 512, 0, stream>>>(hcb, rstart, out);
}

// Round 3
// 305.603 us; speedup vs baseline: 1.1097x; 1.0530x over previous
//
#include <hip/hip_runtime.h>
#include <hip/hip_bf16.h>

#define N_NODES 50000
#define N_EDGES 800000
#define IN_CH 256
#define HID 256
#define OUT_CH 128
#define N_GRAPHS 64
#define SCAN_BLOCKS 196     // ceil(50001/256)
#define M_PAD 50048         // 391 * 128
#define COUNT_BLOCKS 3125   // N_EDGES / 256
#define CVTX_BLOCKS  12512  // M_PAD*64 / 256
#define GEMM1_BLOCKS 782    // 391 * 2

typedef __bf16 bf16x8 __attribute__((ext_vector_type(8)));
typedef float f32x4 __attribute__((ext_vector_type(4)));
typedef float f32x2 __attribute__((ext_vector_type(2)));

// bf16 <-> f32 helpers (RNE on pack)
__device__ __forceinline__ float bf2f(unsigned short u) {
    union { unsigned int i; float f; } x; x.i = ((unsigned int)u) << 16; return x.f;
}
__device__ __forceinline__ unsigned short f2bf(float f) {
    union { float f; unsigned int i; } x; x.f = f;
    unsigned int r = x.i + 0x7FFFu + ((x.i >> 16) & 1u);
    return (unsigned short)(r >> 16);
}

// packed bf16x2 (as uint) -> 2 floats: 1 shift + 1 and
__device__ __forceinline__ float lo_f(unsigned int u) {
    return __uint_as_float(u << 16);
}
__device__ __forceinline__ float hi_f(unsigned int u) {
    return __uint_as_float(u & 0xFFFF0000u);
}

__device__ __forceinline__ void load16(const void* g, void* l) {
    __builtin_amdgcn_global_load_lds(
        (const __attribute__((address_space(1))) void*)g,
        (__attribute__((address_space(3))) void*)l, 16, 0, 0);
}

// final rowptr = block-local exclusive + per-256-chunk offset
__device__ __forceinline__ int rp(const int* __restrict__ rl,
                                  const int* __restrict__ boff, int i) {
    return rl[i] + boff[i >> 8];
}

// ---------------------------------------------------------------------------
// Launch A: histogram of dst WITH per-edge rank recording (blocks 0..3124)
// + x f32->bf16 padded convert (blocks 3125..15636). The atomic's return
// value gives each edge its slot within its dst row -> fill needs no atomics.
// ---------------------------------------------------------------------------
__global__ __launch_bounds__(256) void count_cvtx_kernel(const int* __restrict__ ei,
                                                         int* __restrict__ cnt,
                                                         int* __restrict__ erank,
                                                         const float* __restrict__ x,
                                                         unsigned short* __restrict__ xb) {
    int b = blockIdx.x;
    if (b < COUNT_BLOCKS) {
        int e = b * 256 + threadIdx.x;
        erank[e] = atomicAdd(&cnt[ei[N_EDGES + e]], 1);
        return;
    }
    int i = (b - COUNT_BLOCKS) * 256 + threadIdx.x;    // float4 index
    ushort4 o;
    if (i < N_NODES * (IN_CH / 4)) {
        float4 v = ((const float4*)x)[i];
        o.x = f2bf(v.x); o.y = f2bf(v.y); o.z = f2bf(v.z); o.w = f2bf(v.w);
    } else {
        o = make_ushort4(0, 0, 0, 0);
    }
    ((ushort4*)xb)[i] = o;
}

// ---------------------------------------------------------------------------
// scan_a: block-local exclusive scan; emits dinv/invdeg;
// also graph boundary detection (batch sorted) -> rstart[0..64].
// ---------------------------------------------------------------------------
__global__ __launch_bounds__(256) void scan_a_kernel(const int* __restrict__ cnt,
                                                     int* __restrict__ rl,
                                                     int* __restrict__ blocksum,
                                                     float* __restrict__ dinv,
                                                     float* __restrict__ invdeg,
                                                     const int* __restrict__ batch,
                                                     int* __restrict__ rstart) {
    __shared__ int tmp[256];
    int t = threadIdx.x;
    int i = blockIdx.x * 256 + t;
    int v = (i < N_NODES) ? cnt[i] : 0;
    int x = v;
    tmp[t] = x;
    __syncthreads();
    if (i < N_NODES) {
        int bg = batch[i];
        int bp = (i > 0) ? batch[i - 1] : -1;
        for (int g = bp + 1; g <= bg; g++) rstart[g] = i;   // boundary (rare)
        if (i == N_NODES - 1)
            for (int g = bg + 1; g <= N_GRAPHS; g++) rstart[g] = N_NODES;
    }
#pragma unroll
    for (int off = 1; off < 256; off <<= 1) {
        int y = (t >= off) ? tmp[t - off] : 0;
        __syncthreads();
        x += y;
        tmp[t] = x;
        __syncthreads();
    }
    if (i <= N_NODES) rl[i] = x - v;
    if (i < N_NODES) {
        float d = (float)v + 1.0f;         // +1 self loop
        dinv[i] = rsqrtf(d);
        invdeg[i] = 1.0f / d;
    }
    if (t == 255) blocksum[blockIdx.x] = x;
}

// ---------------------------------------------------------------------------
// blocks 0..383: W1/W2 f32 -> bf16 transposed [N][K].
// block 384: scan of block sums -> blockoff.
// ---------------------------------------------------------------------------
__global__ __launch_bounds__(256) void scanb_cvtw_kernel(
        const int* __restrict__ blocksum, int* __restrict__ blockoff,
        const float* __restrict__ W1, const float* __restrict__ W2,
        unsigned short* __restrict__ w1t, unsigned short* __restrict__ w2t) {
    int t = threadIdx.x;
    if (blockIdx.x < 384) {
        int i = blockIdx.x * 256 + t;                 // 0 .. 98303
        if (i < HID * IN_CH) {                        // W1t[n][k] = W1[k][n]
            int n = i >> 8, k = i & 255;
            w1t[i] = f2bf(W1[k * HID + n]);
        } else {                                      // W2t[n][k] = W2[k][n]
            int j = i - HID * IN_CH;
            int n = j >> 8, k = j & 255;
            w2t[j] = f2bf(W2[k * OUT_CH + n]);
        }
        return;
    }
    __shared__ int tmp[256];
    int v = (t < SCAN_BLOCKS) ? blocksum[t] : 0;
    int x = v;
    tmp[t] = x;
    __syncthreads();
#pragma unroll
    for (int off = 1; off < 256; off <<= 1) {
        int y = (t >= off) ? tmp[t - off] : 0;
        __syncthreads();
        x += y;
        tmp[t] = x;
        __syncthreads();
    }
    if (t < SCAN_BLOCKS) blockoff[t] = x - v;
}

// ---------------------------------------------------------------------------
// GEMM tile body (128x128, 4 waves 2x2, 4x4 mfma_f32_16x16x32_bf16,
// global_load_lds width=16 staging, XOR-swizzled LDS chunks).
// ---------------------------------------------------------------------------
__device__ __forceinline__ void gemm_body(const unsigned short* __restrict__ A,
                                          const unsigned short* __restrict__ Bt,
                                          unsigned short* __restrict__ C,
                                          int N, int bxx, int byy, char* As, char* Bs) {
    const int K = 256;
    int tid = threadIdx.x;
    int bm = bxx * 128;
    int bn = byy * 128;
    int lane = tid & 63, wave = tid >> 6;
    int lane15 = lane & 15, quad = lane >> 4;
    int wm0 = (wave >> 1) << 6;
    int wn0 = (wave & 1) << 6;

    int s1 = tid, s2 = tid + 256;
    int r1 = s1 >> 2, q1 = (s1 & 3) ^ ((r1 >> 1) & 3);
    int r2 = s2 >> 2, q2 = (s2 & 3) ^ ((r2 >> 1) & 3);
    const char* gA1 = (const char*)(A + (size_t)(bm + r1) * K) + (q1 << 4);
    const char* gA2 = (const char*)(A + (size_t)(bm + r2) * K) + (q2 << 4);
    const char* gB1 = (const char*)(Bt + (size_t)(bn + r1) * K) + (q1 << 4);
    const char* gB2 = (const char*)(Bt + (size_t)(bn + r2) * K) + (q2 << 4);
    char* lA1 = As + (wave << 10);
    char* lA2 = As + 4096 + (wave << 10);
    char* lB1 = Bs + (wave << 10);
    char* lB2 = Bs + 4096 + (wave << 10);

    int swm = (lane15 >> 1) & 3;
    f32x4 acc[4][4];
#pragma unroll
    for (int mt = 0; mt < 4; mt++)
#pragma unroll
        for (int nt = 0; nt < 4; nt++)
            acc[mt][nt] = (f32x4){0.f, 0.f, 0.f, 0.f};

    for (int k0 = 0; k0 < K; k0 += 32) {
        __syncthreads();
        load16(gA1 + (k0 << 1), lA1);
        load16(gA2 + (k0 << 1), lA2);
        load16(gB1 + (k0 << 1), lB1);
        load16(gB2 + (k0 << 1), lB2);
        __syncthreads();
        bf16x8 af[4], bfr[4];
#pragma unroll
        for (int t = 0; t < 4; t++) {
            int ra = wm0 + t * 16 + lane15;
            af[t] = *(const bf16x8*)(As + ra * 64 + ((quad ^ swm) << 4));
            int rb = wn0 + t * 16 + lane15;
            bfr[t] = *(const bf16x8*)(Bs + rb * 64 + ((quad ^ swm) << 4));
        }
#pragma unroll
        for (int mt = 0; mt < 4; mt++)
#pragma unroll
            for (int nt = 0; nt < 4; nt++)
                acc[mt][nt] = __builtin_amdgcn_mfma_f32_16x16x32_bf16(
                    af[mt], bfr[nt], acc[mt][nt], 0, 0, 0);
    }

#pragma unroll
    for (int mt = 0; mt < 4; mt++) {
        int rowb = bm + wm0 + mt * 16 + quad * 4;
#pragma unroll
        for (int nt = 0; nt < 4; nt++) {
            int col = bn + wn0 + nt * 16 + lane15;
            f32x4 a = acc[mt][nt];
            C[(size_t)(rowb + 0) * N + col] = f2bf(a[0]);
            C[(size_t)(rowb + 1) * N + col] = f2bf(a[1]);
            C[(size_t)(rowb + 2) * N + col] = f2bf(a[2]);
            C[(size_t)(rowb + 3) * N + col] = f2bf(a[3]);
        }
    }
}

// Launch B: gemm1 tiles (blocks 0..781) + CSR fill (rest, ATOMIC-FREE via
// precomputed ranks); both depend only on the scans.
__global__ __launch_bounds__(256) void fill_gemm1_kernel(
        const int* __restrict__ ei,
        const int* __restrict__ rl,
        const int* __restrict__ boff,
        const int* __restrict__ erank,
        int2* __restrict__ edge2,
        const float* __restrict__ dinv,
        const unsigned short* __restrict__ xb,
        const unsigned short* __restrict__ w1t,
        unsigned short* __restrict__ h1b) {
    __shared__ char As[8192];
    __shared__ char Bs[8192];
    int b = blockIdx.x;
    if (b < GEMM1_BLOCKS) {
        gemm_body(xb, w1t, h1b, HID, b % 391, b / 391, As, Bs);
        return;
    }
    int e = (b - GEMM1_BLOCKS) * 256 + threadIdx.x;
    if (e >= N_EDGES) return;
    int s = ei[e];
    int d = ei[N_EDGES + e];
    int p = rp(rl, boff, d) + erank[e];
    float w = dinv[s] * dinv[d];
    edge2[p] = make_int2(s, __float_as_int(w));
}

// standalone gemm for conv2
__global__ __launch_bounds__(256) void gemm_mfma_kernel(
        const unsigned short* __restrict__ A,
        const unsigned short* __restrict__ Bt,
        unsigned short* __restrict__ C,
        int N) {
    __shared__ char As[8192];
    __shared__ char Bs[8192];
    gemm_body(A, Bt, C, N, blockIdx.x, blockIdx.y, As, Bs);
}

// ---------------------------------------------------------------------------
// GCN aggregation, 256ch (conv1): wave/node, lane = 4ch. Gathers loaded as
// packed uint2 (512B/wave), expanded with shift/mask into f32x4 vector FMA,
// 16-edge unroll, f32 accumulate, ELU, bf16 out.
// ---------------------------------------------------------------------------
__global__ __launch_bounds__(256) void agg1_kernel(const unsigned short* __restrict__ h,
                                                   const float* __restrict__ bias,
                                                   const int* __restrict__ rl,
                                                   const int* __restrict__ boff,
                                                   const int2* __restrict__ edge2,
                                                   const float* __restrict__ invdeg,
                                                   unsigned short* __restrict__ out) {
    int node = blockIdx.x * 4 + (threadIdx.x >> 6);
    if (node >= N_NODES) return;
    int lane = threadIdx.x & 63;
    const uint2* h4 = (const uint2*)h;
    float id = invdeg[node];
    uint2 sv = h4[(size_t)node * 64 + lane];
    f32x4 acc = (f32x4){lo_f(sv.x) * id, hi_f(sv.x) * id,
                        lo_f(sv.y) * id, hi_f(sv.y) * id};
    int e0 = rp(rl, boff, node);
    int e1 = rp(rl, boff, node + 1);
    int e = e0;
    for (; e + 15 < e1; e += 16) {
        int2 ed[16];
        uint2 v[16];
#pragma unroll
        for (int j = 0; j < 16; j++) ed[j] = edge2[e + j];
#pragma unroll
        for (int j = 0; j < 16; j++) v[j] = h4[(size_t)ed[j].x * 64 + lane];
#pragma unroll
        for (int j = 0; j < 16; j++) {
            float w = __int_as_float(ed[j].y);
            f32x4 vf = (f32x4){lo_f(v[j].x), hi_f(v[j].x),
                               lo_f(v[j].y), hi_f(v[j].y)};
            acc += vf * w;
        }
    }
    for (; e + 7 < e1; e += 8) {
        int2 ed[8];
        uint2 v[8];
#pragma unroll
        for (int j = 0; j < 8; j++) ed[j] = edge2[e + j];
#pragma unroll
        for (int j = 0; j < 8; j++) v[j] = h4[(size_t)ed[j].x * 64 + lane];
#pragma unroll
        for (int j = 0; j < 8; j++) {
            float w = __int_as_float(ed[j].y);
            f32x4 vf = (f32x4){lo_f(v[j].x), hi_f(v[j].x),
                               lo_f(v[j].y), hi_f(v[j].y)};
            acc += vf * w;
        }
    }
    for (; e + 3 < e1; e += 4) {
        int2 ed[4];
        uint2 v[4];
#pragma unroll
        for (int j = 0; j < 4; j++) ed[j] = edge2[e + j];
#pragma unroll
        for (int j = 0; j < 4; j++) v[j] = h4[(size_t)ed[j].x * 64 + lane];
#pragma unroll
        for (int j = 0; j < 4; j++) {
            float w = __int_as_float(ed[j].y);
            f32x4 vf = (f32x4){lo_f(v[j].x), hi_f(v[j].x),
                               lo_f(v[j].y), hi_f(v[j].y)};
            acc += vf * w;
        }
    }
    for (; e < e1; e++) {
        int2 ed0 = edge2[e];
        float w0 = __int_as_float(ed0.y);
        uint2 v0 = h4[(size_t)ed0.x * 64 + lane];
        f32x4 vf = (f32x4){lo_f(v0.x), hi_f(v0.x), lo_f(v0.y), hi_f(v0.y)};
        acc += vf * w0;
    }
    float4 bb = ((const float4*)bias)[lane];
    acc[0] += bb.x; acc[1] += bb.y; acc[2] += bb.z; acc[3] += bb.w;
    acc[0] = acc[0] > 0.f ? acc[0] : expm1f(acc[0]);
    acc[1] = acc[1] > 0.f ? acc[1] : expm1f(acc[1]);
    acc[2] = acc[2] > 0.f ? acc[2] : expm1f(acc[2]);
    acc[3] = acc[3] > 0.f ? acc[3] : expm1f(acc[3]);
    ushort4 o;
    o.x = f2bf(acc[0]); o.y = f2bf(acc[1]); o.z = f2bf(acc[2]); o.w = f2bf(acc[3]);
    ((ushort4*)out)[(size_t)node * 64 + lane] = o;
}

// 128ch (conv2): wave/node, lane = 2ch (one packed uint), 16-edge unroll.
__global__ __launch_bounds__(256) void agg2_kernel(const unsigned short* __restrict__ h,
                                                   const float* __restrict__ bias,
                                                   const int* __restrict__ rl,
                                                   const int* __restrict__ boff,
                                                   const int2* __restrict__ edge2,
                                                   const float* __restrict__ invdeg,
                                                   unsigned short* __restrict__ out) {
    int node = blockIdx.x * 4 + (threadIdx.x >> 6);
    if (node >= N_NODES) return;
    int lane = threadIdx.x & 63;
    const unsigned int* h2 = (const unsigned int*)h;
    float id = invdeg[node];
    unsigned int sv = h2[(size_t)node * 64 + lane];
    f32x2 acc = (f32x2){lo_f(sv) * id, hi_f(sv) * id};
    int e0 = rp(rl, boff, node);
    int e1 = rp(rl, boff, node + 1);
    int e = e0;
    for (; e + 15 < e1; e += 16) {
        int2 ed[16];
        unsigned int v[16];
#pragma unroll
        for (int j = 0; j < 16; j++) ed[j] = edge2[e + j];
#pragma unroll
        for (int j = 0; j < 16; j++) v[j] = h2[(size_t)ed[j].x * 64 + lane];
#pragma unroll
        for (int j = 0; j < 16; j++) {
            float w = __int_as_float(ed[j].y);
            acc += (f32x2){lo_f(v[j]), hi_f(v[j])} * w;
        }
    }
    for (; e + 7 < e1; e += 8) {
        int2 ed[8];
        unsigned int v[8];
#pragma unroll
        for (int j = 0; j < 8; j++) ed[j] = edge2[e + j];
#pragma unroll
        for (int j = 0; j < 8; j++) v[j] = h2[(size_t)ed[j].x * 64 + lane];
#pragma unroll
        for (int j = 0; j < 8; j++) {
            float w = __int_as_float(ed[j].y);
            acc += (f32x2){lo_f(v[j]), hi_f(v[j])} * w;
        }
    }
    for (; e + 3 < e1; e += 4) {
        int2 ed[4];
        unsigned int v[4];
#pragma unroll
        for (int j = 0; j < 4; j++) ed[j] = edge2[e + j];
#pragma unroll
        for (int j = 0; j < 4; j++) v[j] = h2[(size_t)ed[j].x * 64 + lane];
#pragma unroll
        for (int j = 0; j < 4; j++) {
            float w = __int_as_float(ed[j].y);
            acc += (f32x2){lo_f(v[j]), hi_f(v[j])} * w;
        }
    }
    for (; e < e1; e++) {
        int2 ed0 = edge2[e];
        float w0 = __int_as_float(ed0.y);
        unsigned int v0 = h2[(size_t)ed0.x * 64 + lane];
        acc += (f32x2){lo_f(v0), hi_f(v0)} * w0;
    }
    float2 bb = ((const float2*)bias)[lane];
    acc[0] += bb.x; acc[1] += bb.y;
    ushort2 o;
    o.x = f2bf(acc[0]); o.y = f2bf(acc[1]);
    ((ushort2*)out)[(size_t)node * 64 + lane] = o;
}

// ---------------------------------------------------------------------------
// Global mean pool: batch is sorted, so graph g owns node range
// [rstart[g], rstart[g+1]). One 512-thread block per graph: contiguous
// streaming reads, zero atomics, divide + write out directly.
// ---------------------------------------------------------------------------
__global__ __launch_bounds__(512) void pool_kernel(const unsigned short* __restrict__ h,
                                                   const int* __restrict__ rstart,
                                                   float* __restrict__ out) {
    int g = blockIdx.x;
    int n0 = rstart[g], n1 = rstart[g + 1];
    int c2 = threadIdx.x & 63;         // packed channel pair 0..63
    int row = threadIdx.x >> 6;        // 0..7
    const unsigned int* h2 = (const unsigned int*)h;
    float ax = 0.f, ay = 0.f;
    for (int n = n0 + row; n < n1; n += 8) {
        unsigned int u = h2[(size_t)n * 64 + c2];
        ax += lo_f(u);
        ay += hi_f(u);
    }
    __shared__ float red[8][128];
    red[row][c2 * 2] = ax;
    red[row][c2 * 2 + 1] = ay;
    __syncthreads();
    if (threadIdx.x < 128) {
        int c = threadIdx.x;
        float s = 0.f;
#pragma unroll
        for (int r = 0; r < 8; r++) s += red[r][c];
        int cn = n1 - n0;
        out[g * OUT_CH + c] = (cn > 0) ? s / (float)cn : 0.f;
    }
}

// ---------------------------------------------------------------------------
extern "C" void kernel_launch(void* const* d_in, const int* in_sizes, int n_in,
                              void* d_out, int out_size, void* d_ws, size_t ws_size,
                              hipStream_t stream) {
    const float* x  = (const float*)d_in[0];
    const float* W1 = (const float*)d_in[1];
    const float* b1 = (const float*)d_in[2];
    const float* W2 = (const float*)d_in[3];
    const float* b2 = (const float*)d_in[4];
    const int*   ei = (const int*)d_in[5];
    const int*   batch = (const int*)d_in[6];
    float* out = (float*)d_out;

    // workspace layout (16B-aligned by construction)
    unsigned short* xb  = (unsigned short*)d_ws;                 // M_PAD*256 bf16
    unsigned short* h1b = xb  + (size_t)M_PAD * IN_CH;           // M_PAD*256 bf16
    unsigned short* hBb = h1b + (size_t)M_PAD * HID;             // M_PAD*256 bf16
    unsigned short* h2b = hBb + (size_t)M_PAD * HID;             // M_PAD*128 bf16
    unsigned short* w1t = h2b + (size_t)M_PAD * OUT_CH;          // 256*256
    unsigned short* w2t = w1t + HID * IN_CH;                     // 128*256
    unsigned short* hcb = xb;   // agg2 bf16 out aliases xb (dead after gemm1)
    float* dinv   = (float*)(w2t + OUT_CH * HID);                // 50000
    float* invdeg = dinv + N_NODES;                              // 50000
    int*   rl     = (int*)(invdeg + N_NODES);                    // 50001 (pad 50016)
    int2*  edge2  = (int2*)(rl + 50016);                         // 800000 int2
    int*   cnt    = (int*)(edge2 + N_EDGES);                     // 50000 (memset)
    int*   erank  = cnt + N_NODES;                               // 800000 (edge ranks)
    int*   blocksum = erank + N_EDGES;                           // 256
    int*   blockoff = blocksum + 256;                            // 256
    int*   rstart   = blockoff + 256;                            // 65 (pad 80)

    hipMemsetAsync(cnt, 0, (size_t)N_NODES * 4, stream);

    // A: histogram+rank + x convert (independent, one launch)
    count_cvtx_kernel<<<COUNT_BLOCKS + CVTX_BLOCKS, 256, 0, stream>>>(ei, cnt, erank, x, xb);
    // scan phase (detects graph boundaries)
    scan_a_kernel<<<SCAN_BLOCKS, 256, 0, stream>>>(cnt, rl, blocksum, dinv, invdeg,
                                                   batch, rstart);
    // weight convert + blocksum scan
    scanb_cvtw_kernel<<<385, 256, 0, stream>>>(blocksum, blockoff, W1, W2, w1t, w2t);
    // B: gemm1 tiles + atomic-free CSR fill (one launch)
    fill_gemm1_kernel<<<GEMM1_BLOCKS + COUNT_BLOCKS, 256, 0, stream>>>(
        ei, rl, blockoff, erank, edge2, dinv, xb, w1t, h1b);
    // conv1 aggregate (+ELU)
    agg1_kernel<<<(N_NODES + 3) / 4, 256, 0, stream>>>(h1b, b1, rl, blockoff,
                                                       edge2, invdeg, hBb);
    // conv2
    dim3 g2(M_PAD / 128, OUT_CH / 128);
    gemm_mfma_kernel<<<g2, 256, 0, stream>>>(hBb, w2t, h2b, OUT_CH);
    agg2_kernel<<<(N_NODES + 3) / 4, 256, 0, stream>>>(h2b, b2, rl, blockoff,
                                                       edge2, invdeg, hcb);
    // mean pool: block-per-graph, no atomics, writes out directly
    pool_kernel<<<N_GRAPHS, 512, 0, stream>>>(hcb, rstart, out);
}

// Round 4
// 297.255 us; speedup vs baseline: 1.1409x; 1.0281x over previous
//
#include <hip/hip_runtime.h>
#include <hip/hip_bf16.h>

#define N_NODES 50000
#define N_EDGES 800000
#define IN_CH 256
#define HID 256
#define OUT_CH 128
#define N_GRAPHS 64
#define SCAN_BLOCKS 196     // ceil(50001/256)
#define M_PAD 50048         // 391 * 128
#define COUNT_BLOCKS 3125   // N_EDGES / 256
#define CVTX_BLOCKS  12512  // M_PAD*64 / 256
#define GEMM1_BLOCKS 782    // 391 * 2
#define SROW 50048          // S row stride (f32)
#define S_QUARTER 12512     // SROW / 4 (50 KB LDS slice)
#define GEMM2_BLOCKS 391
#define SBUILD_BLOCKS 256   // 64 graphs * 4 quarters
#define T2_BLOCKS 391       // 50048 / 128
#define T2_KC 128
#define RED_BLOCKS 128      // 8192 outputs / 64

typedef __bf16 bf16x8 __attribute__((ext_vector_type(8)));
typedef float f32x4 __attribute__((ext_vector_type(4)));
typedef float f32x2 __attribute__((ext_vector_type(2)));
typedef unsigned short u16x8 __attribute__((ext_vector_type(8)));

// bf16 <-> f32 helpers (RNE on pack)
__device__ __forceinline__ float bf2f(unsigned short u) {
    union { unsigned int i; float f; } x; x.i = ((unsigned int)u) << 16; return x.f;
}
__device__ __forceinline__ unsigned short f2bf(float f) {
    union { float f; unsigned int i; } x; x.f = f;
    unsigned int r = x.i + 0x7FFFu + ((x.i >> 16) & 1u);
    return (unsigned short)(r >> 16);
}

// packed bf16x2 (as uint) -> 2 floats: 1 shift + 1 and
__device__ __forceinline__ float lo_f(unsigned int u) {
    return __uint_as_float(u << 16);
}
__device__ __forceinline__ float hi_f(unsigned int u) {
    return __uint_as_float(u & 0xFFFF0000u);
}

__device__ __forceinline__ void load16(const void* g, void* l) {
    __builtin_amdgcn_global_load_lds(
        (const __attribute__((address_space(1))) void*)g,
        (__attribute__((address_space(3))) void*)l, 16, 0, 0);
}

// final rowptr = block-local exclusive + per-256-chunk offset
__device__ __forceinline__ int rp(const int* __restrict__ rl,
                                  const int* __restrict__ boff, int i) {
    return rl[i] + boff[i >> 8];
}

// ---------------------------------------------------------------------------
// Launch A: histogram of dst WITH per-edge rank recording (blocks 0..3124)
// + x f32->bf16 padded convert (blocks 3125..15636). The atomic's return
// value gives each edge its slot within its dst row -> fill needs no atomics.
// ---------------------------------------------------------------------------
__global__ __launch_bounds__(256) void count_cvtx_kernel(const int* __restrict__ ei,
                                                         int* __restrict__ cnt,
                                                         int* __restrict__ erank,
                                                         const float* __restrict__ x,
                                                         unsigned short* __restrict__ xb) {
    int b = blockIdx.x;
    if (b < COUNT_BLOCKS) {
        int e = b * 256 + threadIdx.x;
        erank[e] = atomicAdd(&cnt[ei[N_EDGES + e]], 1);
        return;
    }
    int i = (b - COUNT_BLOCKS) * 256 + threadIdx.x;    // float4 index
    ushort4 o;
    if (i < N_NODES * (IN_CH / 4)) {
        float4 v = ((const float4*)x)[i];
        o.x = f2bf(v.x); o.y = f2bf(v.y); o.z = f2bf(v.z); o.w = f2bf(v.w);
    } else {
        o = make_ushort4(0, 0, 0, 0);
    }
    ((ushort4*)xb)[i] = o;
}

// ---------------------------------------------------------------------------
// scan_a: block-local exclusive scan; emits dinv/invdeg;
// also graph boundary detection (batch sorted) -> rstart[0..64].
// ---------------------------------------------------------------------------
__global__ __launch_bounds__(256) void scan_a_kernel(const int* __restrict__ cnt,
                                                     int* __restrict__ rl,
                                                     int* __restrict__ blocksum,
                                                     float* __restrict__ dinv,
                                                     float* __restrict__ invdeg,
                                                     const int* __restrict__ batch,
                                                     int* __restrict__ rstart) {
    __shared__ int tmp[256];
    int t = threadIdx.x;
    int i = blockIdx.x * 256 + t;
    int v = (i < N_NODES) ? cnt[i] : 0;
    int x = v;
    tmp[t] = x;
    __syncthreads();
    if (i < N_NODES) {
        int bg = batch[i];
        int bp = (i > 0) ? batch[i - 1] : -1;
        for (int g = bp + 1; g <= bg; g++) rstart[g] = i;   // boundary (rare)
        if (i == N_NODES - 1)
            for (int g = bg + 1; g <= N_GRAPHS; g++) rstart[g] = N_NODES;
    }
#pragma unroll
    for (int off = 1; off < 256; off <<= 1) {
        int y = (t >= off) ? tmp[t - off] : 0;
        __syncthreads();
        x += y;
        tmp[t] = x;
        __syncthreads();
    }
    if (i <= N_NODES) rl[i] = x - v;
    if (i < N_NODES) {
        float d = (float)v + 1.0f;         // +1 self loop
        dinv[i] = rsqrtf(d);
        invdeg[i] = 1.0f / d;
    }
    if (t == 255) blocksum[blockIdx.x] = x;
}

// ---------------------------------------------------------------------------
// blocks 0..383: W1/W2 f32 -> bf16 transposed [N][K].
// block 384: scan of block sums -> blockoff.
// ---------------------------------------------------------------------------
__global__ __launch_bounds__(256) void scanb_cvtw_kernel(
        const int* __restrict__ blocksum, int* __restrict__ blockoff,
        const float* __restrict__ W1, const float* __restrict__ W2,
        unsigned short* __restrict__ w1t, unsigned short* __restrict__ w2t) {
    int t = threadIdx.x;
    if (blockIdx.x < 384) {
        int i = blockIdx.x * 256 + t;                 // 0 .. 98303
        if (i < HID * IN_CH) {                        // W1t[n][k] = W1[k][n]
            int n = i >> 8, k = i & 255;
            w1t[i] = f2bf(W1[k * HID + n]);
        } else {                                      // W2t[n][k] = W2[k][n]
            int j = i - HID * IN_CH;
            int n = j >> 8, k = j & 255;
            w2t[j] = f2bf(W2[k * OUT_CH + n]);
        }
        return;
    }
    __shared__ int tmp[256];
    int v = (t < SCAN_BLOCKS) ? blocksum[t] : 0;
    int x = v;
    tmp[t] = x;
    __syncthreads();
#pragma unroll
    for (int off = 1; off < 256; off <<= 1) {
        int y = (t >= off) ? tmp[t - off] : 0;
        __syncthreads();
        x += y;
        tmp[t] = x;
        __syncthreads();
    }
    if (t < SCAN_BLOCKS) blockoff[t] = x - v;
}

// ---------------------------------------------------------------------------
// GEMM tile body (128x128, 4 waves 2x2, 4x4 mfma_f32_16x16x32_bf16,
// global_load_lds width=16 staging, XOR-swizzled LDS chunks).
// TR==0: C[row][col] (row-major, stride N). TR==1: transposed packed store
// h2t[col][row] (stride M_PAD, ushort4 over 4 consecutive rows).
// ---------------------------------------------------------------------------
template <int TR>
__device__ __forceinline__ void gemm_body(const unsigned short* __restrict__ A,
                                          const unsigned short* __restrict__ Bt,
                                          unsigned short* __restrict__ C,
                                          int N, int bxx, int byy, char* As, char* Bs) {
    const int K = 256;
    int tid = threadIdx.x;
    int bm = bxx * 128;
    int bn = byy * 128;
    int lane = tid & 63, wave = tid >> 6;
    int lane15 = lane & 15, quad = lane >> 4;
    int wm0 = (wave >> 1) << 6;
    int wn0 = (wave & 1) << 6;

    int s1 = tid, s2 = tid + 256;
    int r1 = s1 >> 2, q1 = (s1 & 3) ^ ((r1 >> 1) & 3);
    int r2 = s2 >> 2, q2 = (s2 & 3) ^ ((r2 >> 1) & 3);
    const char* gA1 = (const char*)(A + (size_t)(bm + r1) * K) + (q1 << 4);
    const char* gA2 = (const char*)(A + (size_t)(bm + r2) * K) + (q2 << 4);
    const char* gB1 = (const char*)(Bt + (size_t)(bn + r1) * K) + (q1 << 4);
    const char* gB2 = (const char*)(Bt + (size_t)(bn + r2) * K) + (q2 << 4);
    char* lA1 = As + (wave << 10);
    char* lA2 = As + 4096 + (wave << 10);
    char* lB1 = Bs + (wave << 10);
    char* lB2 = Bs + 4096 + (wave << 10);

    int swm = (lane15 >> 1) & 3;
    f32x4 acc[4][4];
#pragma unroll
    for (int mt = 0; mt < 4; mt++)
#pragma unroll
        for (int nt = 0; nt < 4; nt++)
            acc[mt][nt] = (f32x4){0.f, 0.f, 0.f, 0.f};

    for (int k0 = 0; k0 < K; k0 += 32) {
        __syncthreads();
        load16(gA1 + (k0 << 1), lA1);
        load16(gA2 + (k0 << 1), lA2);
        load16(gB1 + (k0 << 1), lB1);
        load16(gB2 + (k0 << 1), lB2);
        __syncthreads();
        bf16x8 af[4], bfr[4];
#pragma unroll
        for (int t = 0; t < 4; t++) {
            int ra = wm0 + t * 16 + lane15;
            af[t] = *(const bf16x8*)(As + ra * 64 + ((quad ^ swm) << 4));
            int rb = wn0 + t * 16 + lane15;
            bfr[t] = *(const bf16x8*)(Bs + rb * 64 + ((quad ^ swm) << 4));
        }
#pragma unroll
        for (int mt = 0; mt < 4; mt++)
#pragma unroll
            for (int nt = 0; nt < 4; nt++)
                acc[mt][nt] = __builtin_amdgcn_mfma_f32_16x16x32_bf16(
                    af[mt], bfr[nt], acc[mt][nt], 0, 0, 0);
    }

#pragma unroll
    for (int mt = 0; mt < 4; mt++) {
        int rowb = bm + wm0 + mt * 16 + quad * 4;
#pragma unroll
        for (int nt = 0; nt < 4; nt++) {
            int col = bn + wn0 + nt * 16 + lane15;
            f32x4 a = acc[mt][nt];
            if (TR == 0) {
                C[(size_t)(rowb + 0) * N + col] = f2bf(a[0]);
                C[(size_t)(rowb + 1) * N + col] = f2bf(a[1]);
                C[(size_t)(rowb + 2) * N + col] = f2bf(a[2]);
                C[(size_t)(rowb + 3) * N + col] = f2bf(a[3]);
            } else {
                ushort4 o;
                o.x = f2bf(a[0]); o.y = f2bf(a[1]);
                o.z = f2bf(a[2]); o.w = f2bf(a[3]);
                *(ushort4*)(C + (size_t)col * M_PAD + rowb) = o;
            }
        }
    }
}

// Launch B: gemm1 tiles (blocks 0..781) + CSR fill (rest, ATOMIC-FREE via
// precomputed ranks); both depend only on the scans.
__global__ __launch_bounds__(256) void fill_gemm1_kernel(
        const int* __restrict__ ei,
        const int* __restrict__ rl,
        const int* __restrict__ boff,
        const int* __restrict__ erank,
        int2* __restrict__ edge2,
        const float* __restrict__ dinv,
        const unsigned short* __restrict__ xb,
        const unsigned short* __restrict__ w1t,
        unsigned short* __restrict__ h1b) {
    __shared__ char As[8192];
    __shared__ char Bs[8192];
    int b = blockIdx.x;
    if (b < GEMM1_BLOCKS) {
        gemm_body<0>(xb, w1t, h1b, HID, b % 391, b / 391, As, Bs);
        return;
    }
    int e = (b - GEMM1_BLOCKS) * 256 + threadIdx.x;
    if (e >= N_EDGES) return;
    int s = ei[e];
    int d = ei[N_EDGES + e];
    int p = rp(rl, boff, d) + erank[e];
    float w = dinv[s] * dinv[d];
    edge2[p] = make_int2(s, __float_as_int(w));
}

// ---------------------------------------------------------------------------
// GCN aggregation, 256ch (conv1): wave/node, lane = 4ch. Gathers loaded as
// packed uint2 (512B/wave), expanded with shift/mask into f32x4 vector FMA,
// 16-edge unroll, f32 accumulate, ELU, bf16 out.
// Grid extended to M_PAD: pad rows zeroed so gemm2's h2t pads are exactly 0
// (S pad cols are 0; 0 x garbage-NaN would poison the t2 MFMA).
// ---------------------------------------------------------------------------
__global__ __launch_bounds__(256) void agg1_kernel(const unsigned short* __restrict__ h,
                                                   const float* __restrict__ bias,
                                                   const int* __restrict__ rl,
                                                   const int* __restrict__ boff,
                                                   const int2* __restrict__ edge2,
                                                   const float* __restrict__ invdeg,
                                                   unsigned short* __restrict__ out) {
    int node = blockIdx.x * 4 + (threadIdx.x >> 6);
    int lane = threadIdx.x & 63;
    if (node >= N_NODES) {
        if (node < M_PAD)
            ((ushort4*)out)[(size_t)node * 64 + lane] = make_ushort4(0, 0, 0, 0);
        return;
    }
    const uint2* h4 = (const uint2*)h;
    float id = invdeg[node];
    uint2 sv = h4[(size_t)node * 64 + lane];
    f32x4 acc = (f32x4){lo_f(sv.x) * id, hi_f(sv.x) * id,
                        lo_f(sv.y) * id, hi_f(sv.y) * id};
    int e0 = rp(rl, boff, node);
    int e1 = rp(rl, boff, node + 1);
    int e = e0;
    for (; e + 15 < e1; e += 16) {
        int2 ed[16];
        uint2 v[16];
#pragma unroll
        for (int j = 0; j < 16; j++) ed[j] = edge2[e + j];
#pragma unroll
        for (int j = 0; j < 16; j++) v[j] = h4[(size_t)ed[j].x * 64 + lane];
#pragma unroll
        for (int j = 0; j < 16; j++) {
            float w = __int_as_float(ed[j].y);
            f32x4 vf = (f32x4){lo_f(v[j].x), hi_f(v[j].x),
                               lo_f(v[j].y), hi_f(v[j].y)};
            acc += vf * w;
        }
    }
    for (; e + 7 < e1; e += 8) {
        int2 ed[8];
        uint2 v[8];
#pragma unroll
        for (int j = 0; j < 8; j++) ed[j] = edge2[e + j];
#pragma unroll
        for (int j = 0; j < 8; j++) v[j] = h4[(size_t)ed[j].x * 64 + lane];
#pragma unroll
        for (int j = 0; j < 8; j++) {
            float w = __int_as_float(ed[j].y);
            f32x4 vf = (f32x4){lo_f(v[j].x), hi_f(v[j].x),
                               lo_f(v[j].y), hi_f(v[j].y)};
            acc += vf * w;
        }
    }
    for (; e + 3 < e1; e += 4) {
        int2 ed[4];
        uint2 v[4];
#pragma unroll
        for (int j = 0; j < 4; j++) ed[j] = edge2[e + j];
#pragma unroll
        for (int j = 0; j < 4; j++) v[j] = h4[(size_t)ed[j].x * 64 + lane];
#pragma unroll
        for (int j = 0; j < 4; j++) {
            float w = __int_as_float(ed[j].y);
            f32x4 vf = (f32x4){lo_f(v[j].x), hi_f(v[j].x),
                               lo_f(v[j].y), hi_f(v[j].y)};
            acc += vf * w;
        }
    }
    for (; e < e1; e++) {
        int2 ed0 = edge2[e];
        float w0 = __int_as_float(ed0.y);
        uint2 v0 = h4[(size_t)ed0.x * 64 + lane];
        f32x4 vf = (f32x4){lo_f(v0.x), hi_f(v0.x), lo_f(v0.y), hi_f(v0.y)};
        acc += vf * w0;
    }
    float4 bb = ((const float4*)bias)[lane];
    acc[0] += bb.x; acc[1] += bb.y; acc[2] += bb.z; acc[3] += bb.w;
    acc[0] = acc[0] > 0.f ? acc[0] : expm1f(acc[0]);
    acc[1] = acc[1] > 0.f ? acc[1] : expm1f(acc[1]);
    acc[2] = acc[2] > 0.f ? acc[2] : expm1f(acc[2]);
    acc[3] = acc[3] > 0.f ? acc[3] : expm1f(acc[3]);
    ushort4 o;
    o.x = f2bf(acc[0]); o.y = f2bf(acc[1]); o.z = f2bf(acc[2]); o.w = f2bf(acc[3]);
    ((ushort4*)out)[(size_t)node * 64 + lane] = o;
}

// ---------------------------------------------------------------------------
// Merged launch: gemm2 tiles (blocks 0..390, h2t transposed output) +
// S-build (blocks 391..646): one block per (graph, column-quarter).
// S[g,s] = invc[g] * (sum_{edges s->d, d in g} w  +  [s in g] * invdeg[s]).
// batch sorted => graph g's CSR edge range is contiguous => block scans it
// with LDS f32 atomics (50 KB slice), zero global atomics, streaming write.
// Both halves independent: sbuild needs edge2 (prev launch), gemm needs hBb.
// ---------------------------------------------------------------------------
__global__ __launch_bounds__(256) void gemm2_sbuild_kernel(
        const unsigned short* __restrict__ A,
        const unsigned short* __restrict__ Bt,
        unsigned short* __restrict__ C,
        const int2* __restrict__ edge2,
        const int* __restrict__ rl,
        const int* __restrict__ boff,
        const int* __restrict__ rstart,
        const float* __restrict__ invdeg,
        float* __restrict__ Sp) {
    __shared__ float srow[S_QUARTER];          // 50048 B; gemm uses first 16 KB
    int b = blockIdx.x;
    if (b < GEMM2_BLOCKS) {
        gemm_body<1>(A, Bt, C, OUT_CH, b, 0, (char*)srow, (char*)srow + 8192);
        return;
    }
    int sb = b - GEMM2_BLOCKS;
    int g = sb >> 2;
    int base = (sb & 3) * S_QUARTER;
    int t = threadIdx.x;
    for (int i = t; i < S_QUARTER; i += 256) srow[i] = 0.f;
    int n0 = rstart[g], n1 = rstart[g + 1];
    __syncthreads();
    int e0 = rp(rl, boff, n0);
    int e1 = rp(rl, boff, n1);
    for (int e = e0 + t; e < e1; e += 256) {
        int2 ed = edge2[e];
        unsigned int s = (unsigned int)(ed.x - base);
        if (s < S_QUARTER)
            atomicAdd(&srow[s], __int_as_float(ed.y));
    }
    __syncthreads();
    float ic = 1.0f / fmaxf((float)(n1 - n0), 1.0f);
    float* Sg = Sp + (size_t)g * SROW + base;
    for (int i = t; i < S_QUARTER; i += 256) {
        float v = srow[i];
        int col = base + i;
        if (col >= n0 && col < n1) v += invdeg[col];   // self-loop term
        Sg[i] = v * ic;
    }
}

// ---------------------------------------------------------------------------
// t2 = S @ h2 : [64 x 50048] x [50048 x 128] MFMA GEMM, K-split over 391
// blocks (Kc=128). A = S (f32, split in-kernel into bf16 hi+lo limbs, two
// MFMAs sharing the B fragment -> ~2^-17 weight error, f32 accumulate).
// B = h2t (k-contiguous rows). Pure streaming: no gathers, no LDS.
// ---------------------------------------------------------------------------
__global__ __launch_bounds__(256) void t2_kernel(const float* __restrict__ Sp,
                                                 const unsigned short* __restrict__ h2t,
                                                 float* __restrict__ part) {
    int b = blockIdx.x;
    int k0 = b * T2_KC;
    int tid = threadIdx.x;
    int lane = tid & 63, wave = tid >> 6;
    int lane15 = lane & 15, quad = lane >> 4;
    int cb = wave << 5;                    // 32 channels per wave
    f32x4 acc[4][2];
#pragma unroll
    for (int m = 0; m < 4; m++) {
        acc[m][0] = (f32x4){0.f, 0.f, 0.f, 0.f};
        acc[m][1] = (f32x4){0.f, 0.f, 0.f, 0.f};
    }
    const unsigned short* hr0 = h2t + (size_t)(cb + lane15) * M_PAD;
    const unsigned short* hr1 = h2t + (size_t)(cb + 16 + lane15) * M_PAD;
#pragma unroll
    for (int ks = 0; ks < T2_KC / 32; ks++) {
        int k = k0 + ks * 32 + quad * 8;
        bf16x8 b0 = *(const bf16x8*)(hr0 + k);
        bf16x8 b1 = *(const bf16x8*)(hr1 + k);
#pragma unroll
        for (int m = 0; m < 4; m++) {
            const float* ap = Sp + (size_t)(m * 16 + lane15) * SROW + k;
            f32x4 v0 = *(const f32x4*)ap;
            f32x4 v1 = *(const f32x4*)(ap + 4);
            u16x8 hu, lu;
#pragma unroll
            for (int j = 0; j < 4; j++) {
                unsigned int e0 = __float_as_uint(v0[j]);
                hu[j] = (unsigned short)(e0 >> 16);                       // trunc hi
                lu[j] = f2bf(v0[j] - __uint_as_float(e0 & 0xFFFF0000u));  // residual
                unsigned int e1 = __float_as_uint(v1[j]);
                hu[j + 4] = (unsigned short)(e1 >> 16);
                lu[j + 4] = f2bf(v1[j] - __uint_as_float(e1 & 0xFFFF0000u));
            }
            bf16x8 ah = __builtin_bit_cast(bf16x8, hu);
            bf16x8 al = __builtin_bit_cast(bf16x8, lu);
            acc[m][0] = __builtin_amdgcn_mfma_f32_16x16x32_bf16(ah, b0, acc[m][0], 0, 0, 0);
            acc[m][0] = __builtin_amdgcn_mfma_f32_16x16x32_bf16(al, b0, acc[m][0], 0, 0, 0);
            acc[m][1] = __builtin_amdgcn_mfma_f32_16x16x32_bf16(ah, b1, acc[m][1], 0, 0, 0);
            acc[m][1] = __builtin_amdgcn_mfma_f32_16x16x32_bf16(al, b1, acc[m][1], 0, 0, 0);
        }
    }
    float* pb = part + (size_t)b * (N_GRAPHS * OUT_CH);
#pragma unroll
    for (int m = 0; m < 4; m++) {
        int g0 = m * 16 + quad * 4;
#pragma unroll
        for (int nt = 0; nt < 2; nt++) {
            int c = cb + nt * 16 + lane15;
            f32x4 a = acc[m][nt];
#pragma unroll
            for (int j = 0; j < 4; j++)
                pb[(g0 + j) * OUT_CH + c] = a[j];
        }
    }
}

// reduce partials over 391 blocks, add bias, empty-graph guard, write out.
__global__ __launch_bounds__(256) void t2red_kernel(const float* __restrict__ part,
                                                    const float* __restrict__ b2,
                                                    const int* __restrict__ rstart,
                                                    float* __restrict__ out) {
    __shared__ float red[4][64];
    int tid = threadIdx.x;
    int q = tid >> 6, l = tid & 63;
    int o = blockIdx.x * 64 + l;
    float s = 0.f;
    for (int i = q; i < T2_BLOCKS; i += 4)
        s += part[(size_t)i * (N_GRAPHS * OUT_CH) + o];
    red[q][l] = s;
    __syncthreads();
    if (tid < 64) {
        float tot = red[0][l] + red[1][l] + red[2][l] + red[3][l];
        int g = o >> 7, c = o & 127;
        out[o] = (rstart[g + 1] > rstart[g]) ? tot + b2[c] : 0.f;
    }
}

// ---------------------------------------------------------------------------
extern "C" void kernel_launch(void* const* d_in, const int* in_sizes, int n_in,
                              void* d_out, int out_size, void* d_ws, size_t ws_size,
                              hipStream_t stream) {
    const float* x  = (const float*)d_in[0];
    const float* W1 = (const float*)d_in[1];
    const float* b1 = (const float*)d_in[2];
    const float* W2 = (const float*)d_in[3];
    const float* b2 = (const float*)d_in[4];
    const int*   ei = (const int*)d_in[5];
    const int*   batch = (const int*)d_in[6];
    float* out = (float*)d_out;

    // workspace layout (16B-aligned by construction)
    unsigned short* xb  = (unsigned short*)d_ws;                 // M_PAD*256 bf16
    unsigned short* h1b = xb  + (size_t)M_PAD * IN_CH;           // M_PAD*256 bf16
    unsigned short* hBb = h1b + (size_t)M_PAD * HID;             // M_PAD*256 bf16
    unsigned short* h2t = hBb + (size_t)M_PAD * HID;             // 128*M_PAD bf16 (transposed)
    unsigned short* w1t = h2t + (size_t)OUT_CH * M_PAD;          // 256*256
    unsigned short* w2t = w1t + HID * IN_CH;                     // 128*256
    float* dinv   = (float*)(w2t + OUT_CH * HID);                // 50000
    float* invdeg = dinv + N_NODES;                              // 50000
    int*   rl     = (int*)(invdeg + N_NODES);                    // 50001 (pad 50016)
    int2*  edge2  = (int2*)(rl + 50016);                         // 800000 int2
    int*   cnt    = (int*)(edge2 + N_EDGES);                     // 50000 (memset)
    int*   erank  = cnt + N_NODES;                               // 800000 (edge ranks)
    int*   blocksum = erank + N_EDGES;                           // 256
    int*   blockoff = blocksum + 256;                            // 256
    int*   rstart   = blockoff + 256;                            // 65 (pad 80)
    float* Sp     = (float*)(rstart + 80);                       // 64*50048 f32
    float* part   = (float*)xb;   // t2 partials alias xb (dead after gemm1)

    hipMemsetAsync(cnt, 0, (size_t)N_NODES * 4, stream);

    // A: histogram+rank + x convert (independent, one launch)
    count_cvtx_kernel<<<COUNT_BLOCKS + CVTX_BLOCKS, 256, 0, stream>>>(ei, cnt, erank, x, xb);
    // scan phase (detects graph boundaries)
    scan_a_kernel<<<SCAN_BLOCKS, 256, 0, stream>>>(cnt, rl, blocksum, dinv, invdeg,
                                                   batch, rstart);
    // weight convert + blocksum scan
    scanb_cvtw_kernel<<<385, 256, 0, stream>>>(blocksum, blockoff, W1, W2, w1t, w2t);
    // B: gemm1 tiles + atomic-free CSR fill (one launch)
    fill_gemm1_kernel<<<GEMM1_BLOCKS + COUNT_BLOCKS, 256, 0, stream>>>(
        ei, rl, blockoff, erank, edge2, dinv, xb, w1t, h1b);
    // conv1 aggregate (+ELU); pads zeroed for the t2 path
    agg1_kernel<<<M_PAD / 4, 256, 0, stream>>>(h1b, b1, rl, blockoff,
                                               edge2, invdeg, hBb);
    // conv2 GEMM (h2t transposed out) + S-build (LDS, no global atomics)
    gemm2_sbuild_kernel<<<GEMM2_BLOCKS + SBUILD_BLOCKS, 256, 0, stream>>>(
        hBb, w2t, h2t, edge2, rl, blockoff, rstart, invdeg, Sp);
    // fused agg2+pool+mean as dense streaming GEMM out = S @ h2 + b2
    t2_kernel<<<T2_BLOCKS, 256, 0, stream>>>(Sp, h2t, part);
    t2red_kernel<<<RED_BLOCKS, 256, 0, stream>>>(part, b2, rstart, out);
}